// Round 1
// baseline (5030.027 us; speedup 1.0000x reference)
//
#include <hip/hip_runtime.h>

#define BB 512
#define SS 168
#define FF 12
#define HH 128
#define UU 256

__device__ __forceinline__ float sigmoidf_(float x){ return 1.f/(1.f+__expf(-x)); }
__device__ __forceinline__ float siluf_(float x){ return x*sigmoidf_(x); }
__device__ __forceinline__ float dot4_(float4 w, float4 v){ return w.x*v.x + w.y*v.y + w.z*v.z + w.w*v.w; }

// ---------------------------------------------------------------------------
// Weight pre-pack: transpose to [i/4][out][4] so per-thread float4 loads are
// coalesced across threads (thread u reads column u).
// ---------------------------------------------------------------------------
__global__ void prep_kernel(const float* __restrict__ Wb0, const float* __restrict__ Wb1,
                            const float* __restrict__ Wff1, const float* __restrict__ Wff2,
                            const float* __restrict__ Wta, const float* __restrict__ Wtb,
                            float* __restrict__ W0p, float* __restrict__ W1p, float* __restrict__ W4p)
{
    int t = blockIdx.x * blockDim.x + threadIdx.x;
    if (t < 35840) {                       // W0p: [35][256][4] <- Wb0 (256 x 140)
        int j = t & 3, u = (t >> 2) & 255, i4 = t >> 10;
        W0p[t] = Wb0[u * 140 + i4 * 4 + j];
    } else if (t < 35840 + 65536) {        // W1p: [64][256][4] <- Wb1 (256 x 256)
        int t2 = t - 35840;
        int j = t2 & 3, u = (t2 >> 2) & 255, i4 = t2 >> 10;
        W1p[t2] = Wb1[u * 256 + i4 * 4 + j];
    } else if (t < 35840 + 65536 + 131072) { // W4p: [64][512][4] <- [Wff1;Wff2;Wta;Wtb]
        int t3 = t - (35840 + 65536);
        int j = t3 & 3, o = (t3 >> 2) & 511, i4 = t3 >> 11;
        int col = i4 * 4 + j;
        float val;
        if      (o < 128) val = Wff1[o * 256 + col];
        else if (o < 256) val = Wff2[(o - 128) * 256 + col];
        else if (o < 384) val = Wta [(o - 256) * 256 + col];
        else              val = Wtb [(o - 384) * 256 + col];
        W4p[t3] = val;
    }
}

// ---------------------------------------------------------------------------
// Stage A: seq-mean + centered input, then sum over 4 periods of
// (conv1d + residual, per-phase segment linear mix), row 0 weights -> x1.
// One block per (b, c), c < 12. Thread tid == time index s.
// ---------------------------------------------------------------------------
__global__ __launch_bounds__(256) void sffA_kernel(
    const float* __restrict__ x,
    const float* __restrict__ c3,  const float* __restrict__ l3,
    const float* __restrict__ c6,  const float* __restrict__ l6,
    const float* __restrict__ c12, const float* __restrict__ l12,
    const float* __restrict__ c24, const float* __restrict__ l24,
    float* __restrict__ meanbuf, float* __restrict__ x1)
{
    int bc = blockIdx.x;
    int b = bc / FF, c = bc % FF;
    __shared__ float v[SS], cv[SS], red[256];
    int tid = threadIdx.x;

    float raw = 0.f;
    if (tid < SS) raw = x[(b * FF + c) * SS + tid];
    red[tid] = raw;
    __syncthreads();
    for (int off = 128; off > 0; off >>= 1) {
        if (tid < off) red[tid] += red[tid + off];
        __syncthreads();
    }
    float mv = red[0] * (1.f / SS);
    if (tid == 0) meanbuf[b * FF + c] = mv;
    if (tid < SS) v[tid] = raw - mv;
    __syncthreads();

    const float* cw[4]  = {c3, c6, c12, c24};
    const float* lwv[4] = {l3, l6, l12, l24};
    const int P[4] = {3, 6, 12, 24};
    float acc = 0.f;
    for (int pi = 0; pi < 4; ++pi) {
        int p = P[pi], pad = p >> 1, k = 1 + 2 * pad, seg = SS / p;
        const float* cwp = cw[pi]; // row 0
        float cc = 0.f;
        if (tid < SS) {
            cc = v[tid];
            for (int j = 0; j < k; ++j) {
                int t = tid + j - pad;
                if (t >= 0 && t < SS) cc += cwp[j] * v[t];
            }
        }
        __syncthreads();           // prior cv readers done
        if (tid < SS) cv[tid] = cc;
        __syncthreads();
        if (tid < SS) {
            int q = tid / p, ph = tid - q * p;
            const float* lwp = lwv[pi]; // row 0
            float a = 0.f;
            for (int kk = 0; kk < seg; ++kk) a += lwp[q * seg + kk] * cv[kk * p + ph];
            acc += a;
        }
    }
    if (tid < SS) x1[(b * SS + tid) * FF + c] = 0.25f * acc;
}

// ---------------------------------------------------------------------------
// Stage B: same sff on xin3 = x1[:,:,:3], weight rows 1 -> x2 and 2 -> x3.
// One block per (b, c), c < 3; computes both outputs in one pass.
// ---------------------------------------------------------------------------
__global__ __launch_bounds__(256) void sffB_kernel(
    const float* __restrict__ x1,
    const float* __restrict__ c3,  const float* __restrict__ l3,
    const float* __restrict__ c6,  const float* __restrict__ l6,
    const float* __restrict__ c12, const float* __restrict__ l12,
    const float* __restrict__ c24, const float* __restrict__ l24,
    float* __restrict__ x2, float* __restrict__ x3)
{
    int bc = blockIdx.x;
    int b = bc / 3, c = bc % 3;
    __shared__ float v[SS], cv[SS];
    int tid = threadIdx.x;
    float raw = 0.f;
    if (tid < SS) raw = x1[(b * SS + tid) * FF + c];
    if (tid < SS) v[tid] = raw;
    __syncthreads();

    const float* cw[4]  = {c3, c6, c12, c24};
    const float* lwv[4] = {l3, l6, l12, l24};
    const int P[4] = {3, 6, 12, 24};
    float acc2 = 0.f, acc3 = 0.f;
    for (int pi = 0; pi < 4; ++pi) {
        int p = P[pi], pad = p >> 1, k = 1 + 2 * pad, seg = SS / p;
        for (int row = 1; row <= 2; ++row) {
            const float* cwp = cw[pi] + row * k;
            float cc = 0.f;
            if (tid < SS) {
                cc = v[tid];
                for (int j = 0; j < k; ++j) {
                    int t = tid + j - pad;
                    if (t >= 0 && t < SS) cc += cwp[j] * v[t];
                }
            }
            __syncthreads();
            if (tid < SS) cv[tid] = cc;
            __syncthreads();
            if (tid < SS) {
                int q = tid / p, ph = tid - q * p;
                const float* lwp = lwv[pi] + row * seg * seg;
                float a = 0.f;
                for (int kk = 0; kk < seg; ++kk) a += lwp[q * seg + kk] * cv[kk * p + ph];
                if (row == 1) acc2 += a; else acc3 += a;
            }
        }
    }
    if (tid < SS) {
        x2[(b * SS + tid) * 3 + c] = 0.25f * acc2;
        x3[(b * SS + tid) * 3 + c] = 0.25f * acc3;
    }
}

// ---------------------------------------------------------------------------
// Recurrent scan: 128 blocks x 256 threads, 4 batch rows per block.
// h lives in LDS (zin[r][12..139]); weights streamed from L2 each step.
// Also computes readout r1[b,s,c] = h @ Wfc[c] + bfc[c] + x3[b,s,c] in-kernel.
// ---------------------------------------------------------------------------
__global__ __launch_bounds__(256) void scan_kernel(
    const float* __restrict__ x1, const float* __restrict__ x3,
    const float* __restrict__ W0p, const float* __restrict__ W1p, const float* __restrict__ W4p,
    const float* __restrict__ bb0, const float* __restrict__ bb1,
    const float* __restrict__ bff1, const float* __restrict__ bff2,
    const float* __restrict__ bta,  const float* __restrict__ btb,
    const float* __restrict__ Wfc,  const float* __restrict__ bfc,
    float* __restrict__ r1)
{
    const int ROWS = 4;
    int b0 = blockIdx.x * ROWS;
    int tid = threadIdx.x;
    __shared__ __align__(16) float zin[ROWS][140];   // [x(12) | h(128)]
    __shared__ __align__(16) float z1s[ROWS][256];
    __shared__ __align__(16) float z2s[ROWS][256];
    __shared__ float ffb[ROWS][128];   // ff2 (tanh) from upper half threads
    __shared__ float tbb2[ROWS][128];  // tb pre-activation
    __shared__ float pr[48];

    for (int idx = tid; idx < ROWS * 128; idx += 256)
        zin[idx >> 7][12 + (idx & 127)] = 0.f;

    float bb0r = bb0[tid];
    float bb1r = bb1[tid];
    float b41 = (tid < 128) ? bff1[tid] : bff2[tid - 128];
    float b42 = (tid < 128) ? bta[tid]  : btb[tid - 128];
    const float4* W0p4 = (const float4*)W0p;
    const float4* W1p4 = (const float4*)W1p;
    const float4* W4p4 = (const float4*)W4p;
    __syncthreads();

    #pragma unroll 1
    for (int s = 0; s < SS; ++s) {
        // phase 0: load x1[b, s, :12]
        if (tid < 48) {
            int r = tid / 12, i = tid % 12;
            zin[r][i] = x1[((b0 + r) * SS + s) * FF + i];
        }
        __syncthreads();

        // phase 1: z1 = silu(Wb0 @ [x;h] + bb0)
        {
            float a0 = bb0r, a1 = bb0r, a2 = bb0r, a3 = bb0r;
            #pragma unroll 7
            for (int i4 = 0; i4 < 35; ++i4) {
                float4 w  = W0p4[i4 * 256 + tid];
                float4 v0 = *(const float4*)&zin[0][i4 * 4];
                float4 v1 = *(const float4*)&zin[1][i4 * 4];
                float4 v2 = *(const float4*)&zin[2][i4 * 4];
                float4 v3 = *(const float4*)&zin[3][i4 * 4];
                a0 += dot4_(w, v0); a1 += dot4_(w, v1);
                a2 += dot4_(w, v2); a3 += dot4_(w, v3);
            }
            z1s[0][tid] = siluf_(a0); z1s[1][tid] = siluf_(a1);
            z1s[2][tid] = siluf_(a2); z1s[3][tid] = siluf_(a3);
        }
        __syncthreads();

        // phase 2: z2 = silu(Wb1 @ z1 + bb1)
        {
            float a0 = bb1r, a1 = bb1r, a2 = bb1r, a3 = bb1r;
            #pragma unroll 8
            for (int i4 = 0; i4 < 64; ++i4) {
                float4 w  = W1p4[i4 * 256 + tid];
                float4 v0 = *(const float4*)&z1s[0][i4 * 4];
                float4 v1 = *(const float4*)&z1s[1][i4 * 4];
                float4 v2 = *(const float4*)&z1s[2][i4 * 4];
                float4 v3 = *(const float4*)&z1s[3][i4 * 4];
                a0 += dot4_(w, v0); a1 += dot4_(w, v1);
                a2 += dot4_(w, v2); a3 += dot4_(w, v3);
            }
            z2s[0][tid] = siluf_(a0); z2s[1][tid] = siluf_(a1);
            z2s[2][tid] = siluf_(a2); z2s[3][tid] = siluf_(a3);
        }
        __syncthreads();

        // phase 3: ff1/ff2/ta/tb (512 outputs = 2 per thread), then h update
        float f0, f1, f2, f3, t0, t1, t2, t3;
        {
            float a0 = b41, a1 = b41, a2 = b41, a3 = b41;
            float c0 = b42, c1 = b42, c2 = b42, c3v = b42;
            #pragma unroll 8
            for (int i4 = 0; i4 < 64; ++i4) {
                float4 w1 = W4p4[i4 * 512 + tid];
                float4 w2 = W4p4[i4 * 512 + 256 + tid];
                float4 v0 = *(const float4*)&z2s[0][i4 * 4];
                float4 v1 = *(const float4*)&z2s[1][i4 * 4];
                float4 v2 = *(const float4*)&z2s[2][i4 * 4];
                float4 v3 = *(const float4*)&z2s[3][i4 * 4];
                a0 += dot4_(w1, v0); a1 += dot4_(w1, v1);
                a2 += dot4_(w1, v2); a3 += dot4_(w1, v3);
                c0 += dot4_(w2, v0); c1 += dot4_(w2, v1);
                c2 += dot4_(w2, v2); c3v += dot4_(w2, v3);
            }
            if (tid < 128) {
                f0 = tanhf(a0); f1 = tanhf(a1); f2 = tanhf(a2); f3 = tanhf(a3);
                t0 = c0; t1 = c1; t2 = c2; t3 = c3v;
            } else {
                int j = tid - 128;
                ffb[0][j] = tanhf(a0); ffb[1][j] = tanhf(a1);
                ffb[2][j] = tanhf(a2); ffb[3][j] = tanhf(a3);
                tbb2[0][j] = c0; tbb2[1][j] = c1; tbb2[2][j] = c2; tbb2[3][j] = c3v;
            }
        }
        __syncthreads();
        if (tid < 128) {
            int j = tid;
            float s0 = sigmoidf_(t0 + tbb2[0][j]);
            float s1 = sigmoidf_(t1 + tbb2[1][j]);
            float s2 = sigmoidf_(t2 + tbb2[2][j]);
            float s3 = sigmoidf_(t3 + tbb2[3][j]);
            zin[0][12 + j] = f0 + s0 * (ffb[0][j] - f0);
            zin[1][12 + j] = f1 + s1 * (ffb[1][j] - f1);
            zin[2][12 + j] = f2 + s2 * (ffb[2][j] - f2);
            zin[3][12 + j] = f3 + s3 * (ffb[3][j] - f3);
        }
        __syncthreads();

        // phase 4a: readout partials (r, c, quarter)
        if (tid < 48) {
            int r = tid / 12, rem = tid % 12, c = rem >> 2, qd = rem & 3;
            const float* wf = Wfc + c * HH + qd * 32;
            const float* hh = &zin[r][12 + qd * 32];
            float pacc = 0.f;
            #pragma unroll
            for (int jj = 0; jj < 32; ++jj) pacc += hh[jj] * wf[jj];
            pr[tid] = pacc;
        }
        __syncthreads();
        // phase 4b: finish readout, add bfc + x3
        if (tid < 12) {
            int r = tid / 3, c = tid % 3;
            int base = r * 12 + c * 4;
            float val = pr[base] + pr[base + 1] + pr[base + 2] + pr[base + 3]
                        + bfc[c] + x3[((b0 + r) * SS + s) * 3 + c];
            r1[((b0 + r) * SS + s) * 3 + c] = val;
        }
        __syncthreads();
    }
}

// ---------------------------------------------------------------------------
// Final: out[b,p,c] = sum_s r1[b,s,c] * Wfits[c,p,s] + mean[b,c] + x2[b,p,c]
// ---------------------------------------------------------------------------
__global__ __launch_bounds__(256) void fits_kernel(
    const float* __restrict__ r1, const float* __restrict__ Wfits,
    const float* __restrict__ x2, const float* __restrict__ meanbuf,
    float* __restrict__ out)
{
    int b = blockIdx.x;
    __shared__ float rb[SS * 3];
    int tid = threadIdx.x;
    for (int idx = tid; idx < SS * 3; idx += 256) rb[idx] = r1[b * SS * 3 + idx];
    __syncthreads();
    for (int o = tid; o < SS * 3; o += 256) {
        int p = o / 3, c = o - p * 3;
        const float* wf = Wfits + (c * SS + p) * SS;
        float acc = 0.f;
        for (int s2 = 0; s2 < SS; ++s2) acc += rb[s2 * 3 + c] * wf[s2];
        out[b * SS * 3 + o] = acc + meanbuf[b * FF + c] + x2[b * SS * 3 + o];
    }
}

extern "C" void kernel_launch(void* const* d_in, const int* in_sizes, int n_in,
                              void* d_out, int out_size, void* d_ws, size_t ws_size,
                              hipStream_t stream) {
    const float* x    = (const float*)d_in[0];
    const float* c3   = (const float*)d_in[1];
    const float* l3   = (const float*)d_in[2];
    const float* c6   = (const float*)d_in[3];
    const float* l6   = (const float*)d_in[4];
    const float* c12  = (const float*)d_in[5];
    const float* l12  = (const float*)d_in[6];
    const float* c24  = (const float*)d_in[7];
    const float* l24  = (const float*)d_in[8];
    const float* Wb0  = (const float*)d_in[9];
    const float* bb0  = (const float*)d_in[10];
    const float* Wb1  = (const float*)d_in[11];
    const float* bb1  = (const float*)d_in[12];
    const float* Wff1 = (const float*)d_in[13];
    const float* bff1 = (const float*)d_in[14];
    const float* Wff2 = (const float*)d_in[15];
    const float* bff2 = (const float*)d_in[16];
    const float* Wta  = (const float*)d_in[17];
    const float* bta  = (const float*)d_in[18];
    const float* Wtb  = (const float*)d_in[19];
    const float* btb  = (const float*)d_in[20];
    const float* Wfc  = (const float*)d_in[21];
    const float* bfc  = (const float*)d_in[22];
    const float* Wfits= (const float*)d_in[23];

    float* ws      = (float*)d_ws;
    float* meanbuf = ws;                    // 6144
    float* x1      = meanbuf + 6144;        // 512*168*12 = 1032192
    float* x2      = x1 + 1032192;          // 258048
    float* x3      = x2 + 258048;           // 258048
    float* r1      = x3 + 258048;           // 258048
    float* W0p     = r1 + 258048;           // 35840
    float* W1p     = W0p + 35840;           // 65536
    float* W4p     = W1p + 65536;           // 131072
    float* out     = (float*)d_out;

    prep_kernel<<<(232448 + 255) / 256, 256, 0, stream>>>(Wb0, Wb1, Wff1, Wff2, Wta, Wtb, W0p, W1p, W4p);
    sffA_kernel<<<BB * FF, 256, 0, stream>>>(x, c3, l3, c6, l6, c12, l12, c24, l24, meanbuf, x1);
    sffB_kernel<<<BB * 3, 256, 0, stream>>>(x1, c3, l3, c6, l6, c12, l12, c24, l24, x2, x3);
    scan_kernel<<<BB / 4, 256, 0, stream>>>(x1, x3, W0p, W1p, W4p,
                                            bb0, bb1, bff1, bff2, bta, btb, Wfc, bfc, r1);
    fits_kernel<<<BB, 256, 0, stream>>>(r1, Wfits, x2, meanbuf, out);
}

// Round 2
// 1376.615 us; speedup vs baseline: 3.6539x; 3.6539x over previous
//
#include <hip/hip_runtime.h>

#define BB 512
#define SS 168
#define FF 12
#define HH 128
#define UU 256

typedef unsigned short u16;
typedef unsigned int   u32;
typedef _Float16 half2_t __attribute__((ext_vector_type(2)));

__device__ __forceinline__ float sigmoidf_(float x){ return __fdividef(1.f, 1.f + __expf(-x)); }
__device__ __forceinline__ float siluf_(float x){ return x * sigmoidf_(x); }
__device__ __forceinline__ float tanhf_(float x){
    float t = __expf(-2.f * fabsf(x));
    float y = __fdividef(1.f - t, 1.f + t);
    return copysignf(y, x);
}
__device__ __forceinline__ u16 f2h_(float v){ return __builtin_bit_cast(u16, (_Float16)v); }

__device__ __forceinline__ float fdot2_(u32 w, u32 v, float acc){
#if __has_builtin(__builtin_amdgcn_fdot2)
    return __builtin_amdgcn_fdot2(__builtin_bit_cast(half2_t, w),
                                  __builtin_bit_cast(half2_t, v), acc, false);
#else
    half2_t a = __builtin_bit_cast(half2_t, w), b = __builtin_bit_cast(half2_t, v);
    return acc + (float)a.x * (float)b.x + (float)a.y * (float)b.y;
#endif
}

// ---------------------------------------------------------------------------
// Weight pre-pack to fp16: W0h [18][256][8], W1h [32][256][8], W4h [32][512][8]
// (K-major blocks of 8 halves per output column; zero-padded K for W0).
// ---------------------------------------------------------------------------
__global__ void prep_kernel(const float* __restrict__ Wb0, const float* __restrict__ Wb1,
                            const float* __restrict__ Wff1, const float* __restrict__ Wff2,
                            const float* __restrict__ Wta, const float* __restrict__ Wtb,
                            u16* __restrict__ W0h, u16* __restrict__ W1h, u16* __restrict__ W4h)
{
    int t = blockIdx.x * blockDim.x + threadIdx.x;
    if (t < 36864) {                       // [18][256][8] <- Wb0 (256 x 140, pad to 144)
        int j = t & 7, u = (t >> 3) & 255, i8 = t >> 11;
        int col = i8 * 8 + j;
        float v = (col < 140) ? Wb0[u * 140 + col] : 0.f;
        W0h[t] = f2h_(v);
    } else if (t < 36864 + 65536) {        // [32][256][8] <- Wb1 (256 x 256)
        int t2 = t - 36864;
        int j = t2 & 7, u = (t2 >> 3) & 255, i8 = t2 >> 11;
        W1h[t2] = f2h_(Wb1[u * 256 + i8 * 8 + j]);
    } else if (t < 36864 + 65536 + 131072) { // [32][512][8] <- [Wff1;Wff2;Wta;Wtb]
        int t3 = t - 102400;
        int j = t3 & 7, o = (t3 >> 3) & 511, i8 = t3 >> 12;
        int col = i8 * 8 + j;
        float v;
        if      (o < 128) v = Wff1[o * 256 + col];
        else if (o < 256) v = Wff2[(o - 128) * 256 + col];
        else if (o < 384) v = Wta [(o - 256) * 256 + col];
        else              v = Wtb [(o - 384) * 256 + col];
        W4h[t3] = f2h_(v);
    }
}

// ---------------------------------------------------------------------------
// Stage A (unchanged): seq-mean + centered input, 4-period sff row 0 -> x1.
// ---------------------------------------------------------------------------
__global__ __launch_bounds__(256) void sffA_kernel(
    const float* __restrict__ x,
    const float* __restrict__ c3,  const float* __restrict__ l3,
    const float* __restrict__ c6,  const float* __restrict__ l6,
    const float* __restrict__ c12, const float* __restrict__ l12,
    const float* __restrict__ c24, const float* __restrict__ l24,
    float* __restrict__ meanbuf, float* __restrict__ x1)
{
    int bc = blockIdx.x;
    int b = bc / FF, c = bc % FF;
    __shared__ float v[SS], cv[SS], red[256];
    int tid = threadIdx.x;

    float raw = 0.f;
    if (tid < SS) raw = x[(b * FF + c) * SS + tid];
    red[tid] = raw;
    __syncthreads();
    for (int off = 128; off > 0; off >>= 1) {
        if (tid < off) red[tid] += red[tid + off];
        __syncthreads();
    }
    float mv = red[0] * (1.f / SS);
    if (tid == 0) meanbuf[b * FF + c] = mv;
    if (tid < SS) v[tid] = raw - mv;
    __syncthreads();

    const float* cw[4]  = {c3, c6, c12, c24};
    const float* lwv[4] = {l3, l6, l12, l24};
    const int P[4] = {3, 6, 12, 24};
    float acc = 0.f;
    for (int pi = 0; pi < 4; ++pi) {
        int p = P[pi], pad = p >> 1, k = 1 + 2 * pad, seg = SS / p;
        const float* cwp = cw[pi];
        float cc = 0.f;
        if (tid < SS) {
            cc = v[tid];
            for (int j = 0; j < k; ++j) {
                int t = tid + j - pad;
                if (t >= 0 && t < SS) cc += cwp[j] * v[t];
            }
        }
        __syncthreads();
        if (tid < SS) cv[tid] = cc;
        __syncthreads();
        if (tid < SS) {
            int q = tid / p, ph = tid - q * p;
            const float* lwp = lwv[pi];
            float a = 0.f;
            for (int kk = 0; kk < seg; ++kk) a += lwp[q * seg + kk] * cv[kk * p + ph];
            acc += a;
        }
    }
    if (tid < SS) x1[(b * SS + tid) * FF + c] = 0.25f * acc;
}

// ---------------------------------------------------------------------------
// Stage B (unchanged): sff rows 1,2 on x1[:,:,:3] -> x2, x3.
// ---------------------------------------------------------------------------
__global__ __launch_bounds__(256) void sffB_kernel(
    const float* __restrict__ x1,
    const float* __restrict__ c3,  const float* __restrict__ l3,
    const float* __restrict__ c6,  const float* __restrict__ l6,
    const float* __restrict__ c12, const float* __restrict__ l12,
    const float* __restrict__ c24, const float* __restrict__ l24,
    float* __restrict__ x2, float* __restrict__ x3)
{
    int bc = blockIdx.x;
    int b = bc / 3, c = bc % 3;
    __shared__ float v[SS], cv[SS];
    int tid = threadIdx.x;
    float raw = 0.f;
    if (tid < SS) raw = x1[(b * SS + tid) * FF + c];
    if (tid < SS) v[tid] = raw;
    __syncthreads();

    const float* cw[4]  = {c3, c6, c12, c24};
    const float* lwv[4] = {l3, l6, l12, l24};
    const int P[4] = {3, 6, 12, 24};
    float acc2 = 0.f, acc3 = 0.f;
    for (int pi = 0; pi < 4; ++pi) {
        int p = P[pi], pad = p >> 1, k = 1 + 2 * pad, seg = SS / p;
        for (int row = 1; row <= 2; ++row) {
            const float* cwp = cw[pi] + row * k;
            float cc = 0.f;
            if (tid < SS) {
                cc = v[tid];
                for (int j = 0; j < k; ++j) {
                    int t = tid + j - pad;
                    if (t >= 0 && t < SS) cc += cwp[j] * v[t];
                }
            }
            __syncthreads();
            if (tid < SS) cv[tid] = cc;
            __syncthreads();
            if (tid < SS) {
                int q = tid / p, ph = tid - q * p;
                const float* lwp = lwv[pi] + row * seg * seg;
                float a = 0.f;
                for (int kk = 0; kk < seg; ++kk) a += lwp[q * seg + kk] * cv[kk * p + ph];
                if (row == 1) acc2 += a; else acc3 += a;
            }
        }
    }
    if (tid < SS) {
        x2[(b * SS + tid) * 3 + c] = 0.25f * acc2;
        x3[(b * SS + tid) * 3 + c] = 0.25f * acc3;
    }
}

// ---------------------------------------------------------------------------
// Recurrent scan: 128 blocks x 512 threads, 4 batch rows per block.
// fp16 weights streamed from L2 via fdot2; all per-step data LDS-resident.
// Phases 1/2 split K across two 256-thread halves; phase 3 is 1 out/thread.
// ---------------------------------------------------------------------------
__global__ __launch_bounds__(512) void scan_kernel(
    const float* __restrict__ x1g, const float* __restrict__ x3g,
    const u16* __restrict__ W0h, const u16* __restrict__ W1h, const u16* __restrict__ W4h,
    const float* __restrict__ bb0, const float* __restrict__ bb1,
    const float* __restrict__ bff1, const float* __restrict__ bff2,
    const float* __restrict__ bta,  const float* __restrict__ btb,
    const float* __restrict__ Wfc,  const float* __restrict__ bfc,
    float* __restrict__ r1g)
{
    const int b0 = blockIdx.x * 4;
    const int tid = threadIdx.x;

    __shared__ __align__(16) u16 xh[4][2016];      // x1 slice as fp16
    __shared__ float x3s[4][504];
    __shared__ float r1s[4][504];
    __shared__ __align__(16) u16 zin[4][144];      // [x(12) | h(128) | pad(4)]
    __shared__ __align__(16) u16 z1h[4][256];
    __shared__ __align__(16) u16 z2h[4][256];
    __shared__ __align__(16) float scratch[2048];  // ps[2][4][256] / pre3[4][512]
    __shared__ float hfs[512];                     // h (f32) for readout
    __shared__ float bb0s[256], bb1s[256], b4s[512];
    __shared__ float wfcs[384];
    __shared__ float bfcs[4];

    const uint4* W0h4 = (const uint4*)W0h;
    const uint4* W1h4 = (const uint4*)W1h;
    const uint4* W4h4 = (const uint4*)W4h;

    // ---- prologue: preload everything ----
    if (tid < 256) { bb0s[tid] = bb0[tid]; bb1s[tid] = bb1[tid]; }
    {
        int o = tid;
        float v;
        if      (o < 128) v = bff1[o];
        else if (o < 256) v = bff2[o - 128];
        else if (o < 384) v = bta[o - 256];
        else              v = btb[o - 384];
        b4s[o] = v;
    }
    if (tid < 384) wfcs[tid] = Wfc[tid];
    if (tid < 3)   bfcs[tid] = bfc[tid];
    hfs[tid] = 0.f;
    for (int idx = tid; idx < 4 * 132; idx += 512) {
        int r = idx / 132, i = idx % 132;
        zin[r][12 + i] = 0;                        // h = 0, pad = 0
    }
    for (int idx = tid; idx < 4 * 2016; idx += 512) {
        int r = idx / 2016, rem = idx % 2016;
        xh[r][rem] = f2h_(x1g[(b0 + r) * 2016 + rem]);
    }
    for (int idx = tid; idx < 4 * 504; idx += 512) {
        int r = idx / 504, rem = idx % 504;
        x3s[r][rem] = x3g[(b0 + r) * 504 + rem];
    }
    __syncthreads();
    if (tid < 48) {                                // x for s=0
        int r = tid / 12, i = tid % 12;
        zin[r][i] = xh[r][i];
    }
    __syncthreads();

    const int u  = tid & 255;
    const int kh = tid >> 8;

    #pragma unroll 1
    for (int s = 0; s < SS; ++s) {
        // ---- P1: z1 partial dots (split K) + readout of previous step ----
        {
            float a0 = 0.f, a1 = 0.f, a2 = 0.f, a3 = 0.f;
            const uint4* wp = W0h4 + (kh * 9) * 256 + u;
            const int vb = kh * 72;
            #pragma unroll
            for (int it = 0; it < 9; ++it) {
                uint4 w  = wp[it * 256];
                uint4 v0 = *(const uint4*)&zin[0][vb + it * 8];
                uint4 v1 = *(const uint4*)&zin[1][vb + it * 8];
                uint4 v2 = *(const uint4*)&zin[2][vb + it * 8];
                uint4 v3 = *(const uint4*)&zin[3][vb + it * 8];
                a0 = fdot2_(w.x, v0.x, a0); a0 = fdot2_(w.y, v0.y, a0);
                a0 = fdot2_(w.z, v0.z, a0); a0 = fdot2_(w.w, v0.w, a0);
                a1 = fdot2_(w.x, v1.x, a1); a1 = fdot2_(w.y, v1.y, a1);
                a1 = fdot2_(w.z, v1.z, a1); a1 = fdot2_(w.w, v1.w, a1);
                a2 = fdot2_(w.x, v2.x, a2); a2 = fdot2_(w.y, v2.y, a2);
                a2 = fdot2_(w.z, v2.z, a2); a2 = fdot2_(w.w, v2.w, a2);
                a3 = fdot2_(w.x, v3.x, a3); a3 = fdot2_(w.y, v3.y, a3);
                a3 = fdot2_(w.z, v3.z, a3); a3 = fdot2_(w.w, v3.w, a3);
            }
            scratch[kh * 1024 + 0 * 256 + u] = a0;
            scratch[kh * 1024 + 1 * 256 + u] = a1;
            scratch[kh * 1024 + 2 * 256 + u] = a2;
            scratch[kh * 1024 + 3 * 256 + u] = a3;
        }
        if (s > 0 && tid < 384) {                  // readout for step s-1 (h in hfs)
            int g = tid >> 5, l = tid & 31;
            int r = g / 3, c = g % 3;
            const float* hh = &hfs[r * 128 + l * 4];
            const float* wf = &wfcs[c * 128 + l * 4];
            float val = hh[0]*wf[0] + hh[1]*wf[1] + hh[2]*wf[2] + hh[3]*wf[3];
            for (int off = 16; off > 0; off >>= 1) val += __shfl_down(val, off, 32);
            if (l == 0)
                r1s[r][(s - 1) * 3 + c] = val + bfcs[c] + x3s[r][(s - 1) * 3 + c];
        }
        __syncthreads();

        // ---- C1: combine halves + bias + silu -> z1h ----
        #pragma unroll
        for (int kk = 0; kk < 2; ++kk) {
            int idx = tid + kk * 512;
            int uu = idx & 255, r = idx >> 8;
            float val = scratch[r * 256 + uu] + scratch[1024 + r * 256 + uu] + bb0s[uu];
            z1h[r][uu] = f2h_(siluf_(val));
        }
        __syncthreads();

        // ---- P2: z2 partial dots (split K) ----
        {
            float a0 = 0.f, a1 = 0.f, a2 = 0.f, a3 = 0.f;
            const uint4* wp = W1h4 + (kh * 16) * 256 + u;
            const int vb = kh * 128;
            #pragma unroll
            for (int it = 0; it < 16; ++it) {
                uint4 w  = wp[it * 256];
                uint4 v0 = *(const uint4*)&z1h[0][vb + it * 8];
                uint4 v1 = *(const uint4*)&z1h[1][vb + it * 8];
                uint4 v2 = *(const uint4*)&z1h[2][vb + it * 8];
                uint4 v3 = *(const uint4*)&z1h[3][vb + it * 8];
                a0 = fdot2_(w.x, v0.x, a0); a0 = fdot2_(w.y, v0.y, a0);
                a0 = fdot2_(w.z, v0.z, a0); a0 = fdot2_(w.w, v0.w, a0);
                a1 = fdot2_(w.x, v1.x, a1); a1 = fdot2_(w.y, v1.y, a1);
                a1 = fdot2_(w.z, v1.z, a1); a1 = fdot2_(w.w, v1.w, a1);
                a2 = fdot2_(w.x, v2.x, a2); a2 = fdot2_(w.y, v2.y, a2);
                a2 = fdot2_(w.z, v2.z, a2); a2 = fdot2_(w.w, v2.w, a2);
                a3 = fdot2_(w.x, v3.x, a3); a3 = fdot2_(w.y, v3.y, a3);
                a3 = fdot2_(w.z, v3.z, a3); a3 = fdot2_(w.w, v3.w, a3);
            }
            scratch[kh * 1024 + 0 * 256 + u] = a0;
            scratch[kh * 1024 + 1 * 256 + u] = a1;
            scratch[kh * 1024 + 2 * 256 + u] = a2;
            scratch[kh * 1024 + 3 * 256 + u] = a3;
        }
        __syncthreads();

        // ---- C2: combine + bias + silu -> z2h ----
        #pragma unroll
        for (int kk = 0; kk < 2; ++kk) {
            int idx = tid + kk * 512;
            int uu = idx & 255, r = idx >> 8;
            float val = scratch[r * 256 + uu] + scratch[1024 + r * 256 + uu] + bb1s[uu];
            z2h[r][uu] = f2h_(siluf_(val));
        }
        __syncthreads();

        // ---- P3: ff1/ff2/ta/tb pre-activations (512 outs, 1 per thread) ----
        {
            float a0 = 0.f, a1 = 0.f, a2 = 0.f, a3 = 0.f;
            const uint4* wp = W4h4 + tid;
            #pragma unroll
            for (int it = 0; it < 32; ++it) {
                uint4 w  = wp[it * 512];
                uint4 v0 = *(const uint4*)&z2h[0][it * 8];
                uint4 v1 = *(const uint4*)&z2h[1][it * 8];
                uint4 v2 = *(const uint4*)&z2h[2][it * 8];
                uint4 v3 = *(const uint4*)&z2h[3][it * 8];
                a0 = fdot2_(w.x, v0.x, a0); a0 = fdot2_(w.y, v0.y, a0);
                a0 = fdot2_(w.z, v0.z, a0); a0 = fdot2_(w.w, v0.w, a0);
                a1 = fdot2_(w.x, v1.x, a1); a1 = fdot2_(w.y, v1.y, a1);
                a1 = fdot2_(w.z, v1.z, a1); a1 = fdot2_(w.w, v1.w, a1);
                a2 = fdot2_(w.x, v2.x, a2); a2 = fdot2_(w.y, v2.y, a2);
                a2 = fdot2_(w.z, v2.z, a2); a2 = fdot2_(w.w, v2.w, a2);
                a3 = fdot2_(w.x, v3.x, a3); a3 = fdot2_(w.y, v3.y, a3);
                a3 = fdot2_(w.z, v3.z, a3); a3 = fdot2_(w.w, v3.w, a3);
            }
            scratch[0 * 512 + tid] = a0;
            scratch[1 * 512 + tid] = a1;
            scratch[2 * 512 + tid] = a2;
            scratch[3 * 512 + tid] = a3;
        }
        __syncthreads();

        // ---- C3: h update + x copy for next step ----
        {
            int r = tid >> 7, j = tid & 127;
            float a1v = scratch[r * 512 + j]       + b4s[j];
            float a2v = scratch[r * 512 + 128 + j] + b4s[128 + j];
            float a3v = scratch[r * 512 + 256 + j] + b4s[256 + j];
            float a4v = scratch[r * 512 + 384 + j] + b4s[384 + j];
            float ff1 = tanhf_(a1v);
            float ff2 = tanhf_(a2v);
            float tt  = sigmoidf_(a3v + a4v);
            float h   = ff1 + tt * (ff2 - ff1);
            hfs[r * 128 + j] = h;
            zin[r][12 + j] = f2h_(h);
        }
        if (s < SS - 1 && tid < 48) {
            int r = tid / 12, i = tid % 12;
            zin[r][i] = xh[r][(s + 1) * 12 + i];
        }
        __syncthreads();
    }

    // ---- epilogue: readout for s = 167, then write r1 ----
    if (tid < 384) {
        int g = tid >> 5, l = tid & 31;
        int r = g / 3, c = g % 3;
        const float* hh = &hfs[r * 128 + l * 4];
        const float* wf = &wfcs[c * 128 + l * 4];
        float val = hh[0]*wf[0] + hh[1]*wf[1] + hh[2]*wf[2] + hh[3]*wf[3];
        for (int off = 16; off > 0; off >>= 1) val += __shfl_down(val, off, 32);
        if (l == 0)
            r1s[r][167 * 3 + c] = val + bfcs[c] + x3s[r][167 * 3 + c];
    }
    __syncthreads();
    for (int idx = tid; idx < 4 * 504; idx += 512) {
        int r = idx / 504, rem = idx % 504;
        r1g[(b0 + r) * 504 + rem] = r1s[r][rem];
    }
}

// ---------------------------------------------------------------------------
// Final fits einsum, tiled: grid = 8 btiles x 3 c x 6 ptiles.
// out[b,p,c] = sum_s r1[b,s,c] * Wfits[c,p,s] + mean[b,c] + x2[b,p,c]
// ---------------------------------------------------------------------------
__global__ __launch_bounds__(256) void fits_kernel(
    const float* __restrict__ r1, const float* __restrict__ Wfits,
    const float* __restrict__ x2, const float* __restrict__ meanbuf,
    float* __restrict__ out)
{
    int bid = blockIdx.x;
    int bt = bid & 7;
    int rest = bid >> 3;
    int c = rest % 3;
    int pt = rest / 3;
    int b0 = bt * 64, p0 = pt * 28;
    __shared__ float rT[168][65];
    __shared__ float wT[28][168];
    int t = threadIdx.x;
    for (int idx = t; idx < 64 * 168; idx += 256) {
        int b = idx / 168, s = idx - b * 168;
        rT[s][b] = r1[((b0 + b) * 168 + s) * 3 + c];
    }
    for (int idx = t; idx < 28 * 168; idx += 256) {
        int p = idx / 168, s = idx - p * 168;
        wT[p][s] = Wfits[(c * 168 + p0 + p) * 168 + s];
    }
    __syncthreads();
    int b = t & 63, pq = t >> 6;
    float acc[7] = {0, 0, 0, 0, 0, 0, 0};
    for (int s = 0; s < 168; ++s) {
        float v = rT[s][b];
        #pragma unroll
        for (int j = 0; j < 7; ++j) acc[j] += v * wT[pq * 7 + j][s];
    }
    float mb = meanbuf[(b0 + b) * 12 + c];
    #pragma unroll
    for (int j = 0; j < 7; ++j) {
        int p = p0 + pq * 7 + j;
        int gi = ((b0 + b) * 168 + p) * 3 + c;
        out[gi] = acc[j] + mb + x2[gi];
    }
}

extern "C" void kernel_launch(void* const* d_in, const int* in_sizes, int n_in,
                              void* d_out, int out_size, void* d_ws, size_t ws_size,
                              hipStream_t stream) {
    const float* x    = (const float*)d_in[0];
    const float* c3   = (const float*)d_in[1];
    const float* l3   = (const float*)d_in[2];
    const float* c6   = (const float*)d_in[3];
    const float* l6   = (const float*)d_in[4];
    const float* c12  = (const float*)d_in[5];
    const float* l12  = (const float*)d_in[6];
    const float* c24  = (const float*)d_in[7];
    const float* l24  = (const float*)d_in[8];
    const float* Wb0  = (const float*)d_in[9];
    const float* bb0  = (const float*)d_in[10];
    const float* Wb1  = (const float*)d_in[11];
    const float* bb1  = (const float*)d_in[12];
    const float* Wff1 = (const float*)d_in[13];
    const float* bff1 = (const float*)d_in[14];
    const float* Wff2 = (const float*)d_in[15];
    const float* bff2 = (const float*)d_in[16];
    const float* Wta  = (const float*)d_in[17];
    const float* bta  = (const float*)d_in[18];
    const float* Wtb  = (const float*)d_in[19];
    const float* btb  = (const float*)d_in[20];
    const float* Wfc  = (const float*)d_in[21];
    const float* bfc  = (const float*)d_in[22];
    const float* Wfits= (const float*)d_in[23];

    float* ws      = (float*)d_ws;
    float* meanbuf = ws;                    // 6144
    float* x1      = meanbuf + 6144;        // 1032192
    float* x2      = x1 + 1032192;          // 258048
    float* x3      = x2 + 258048;           // 258048
    float* r1      = x3 + 258048;           // 258048
    u16*   W0h     = (u16*)(r1 + 258048);   // 36864 u16
    u16*   W1h     = W0h + 36864;           // 65536 u16
    u16*   W4h     = W1h + 65536;           // 131072 u16
    float* out     = (float*)d_out;

    prep_kernel<<<(233472 + 255) / 256, 256, 0, stream>>>(Wb0, Wb1, Wff1, Wff2, Wta, Wtb, W0h, W1h, W4h);
    sffA_kernel<<<BB * FF, 256, 0, stream>>>(x, c3, l3, c6, l6, c12, l12, c24, l24, meanbuf, x1);
    sffB_kernel<<<BB * 3, 256, 0, stream>>>(x1, c3, l3, c6, l6, c12, l12, c24, l24, x2, x3);
    scan_kernel<<<BB / 4, 512, 0, stream>>>(x1, x3, W0h, W1h, W4h,
                                            bb0, bb1, bff1, bff2, bta, btb, Wfc, bfc, r1);
    fits_kernel<<<144, 256, 0, stream>>>(r1, Wfits, x2, meanbuf, out);
}

// Round 3
// 642.414 us; speedup vs baseline: 7.8299x; 2.1429x over previous
//
#include <hip/hip_runtime.h>

#define BB 512
#define SS 168
#define FF 12
#define HH 128
#define UU 256

typedef unsigned short u16;
typedef unsigned int   u32;
typedef _Float16 f16x8 __attribute__((ext_vector_type(8)));
typedef float    f32x4 __attribute__((ext_vector_type(4)));

__device__ __forceinline__ float sigmoidf_(float x){ return __fdividef(1.f, 1.f + __expf(-x)); }
__device__ __forceinline__ float siluf_(float x){ return x * sigmoidf_(x); }
__device__ __forceinline__ float tanhf_(float x){
    float t = __expf(-2.f * fabsf(x));
    float y = __fdividef(1.f - t, 1.f + t);
    return copysignf(y, x);
}
__device__ __forceinline__ u16 f2h_(float v){ return __builtin_bit_cast(u16, (_Float16)v); }
__device__ __forceinline__ f16x8 bc8_(uint4 v){ return __builtin_bit_cast(f16x8, v); }

#define MFMA16(a, b, acc) __builtin_amdgcn_mfma_f32_16x16x32_f16((a), (b), (acc), 0, 0, 0)

// ---------------------------------------------------------------------------
// Weight pre-pack into MFMA B-fragment order (fp16).
// Fragment tile (t, kstep s): elem (col c, kgroup g, e) at
//   flat = (t*NS + s)*512 + c*32 + g*8 + e   [512 u16 = 1KB per (t,s)]
// Lane L reads uint4 at (t*NS+s)*64 + (L&15)*4 + (L>>4)  -> bijective 1KB.
// W0f: 16 tiles x 5 ksteps (K=160, zero pad k>=140)  = 40960 u16
// W1f: 16 tiles x 8 ksteps (K=256)                   = 65536 u16
// W4f: 32 tiles x 8 ksteps ([ff1;ff2;ta;tb], K=256)  = 131072 u16
// ---------------------------------------------------------------------------
__global__ void prep_kernel(const float* __restrict__ Wb0, const float* __restrict__ Wb1,
                            const float* __restrict__ Wff1, const float* __restrict__ Wff2,
                            const float* __restrict__ Wta, const float* __restrict__ Wtb,
                            u16* __restrict__ W0f, u16* __restrict__ W1f, u16* __restrict__ W4f)
{
    int t = blockIdx.x * blockDim.x + threadIdx.x;
    if (t < 40960) {
        int e = t & 7, g = (t >> 3) & 3, c = (t >> 5) & 15, rest = t >> 9;
        int s = rest % 5, tt = rest / 5;
        int u = tt * 16 + c, k = s * 32 + g * 8 + e;
        W0f[t] = f2h_((k < 140) ? Wb0[u * 140 + k] : 0.f);
    } else if (t < 40960 + 65536) {
        int t1 = t - 40960;
        int e = t1 & 7, g = (t1 >> 3) & 3, c = (t1 >> 5) & 15, rest = t1 >> 9;
        int s = rest & 7, tt = rest >> 3;
        int u = tt * 16 + c, k = s * 32 + g * 8 + e;
        W1f[t1] = f2h_(Wb1[u * 256 + k]);
    } else if (t < 40960 + 65536 + 131072) {
        int t2 = t - 106496;
        int e = t2 & 7, g = (t2 >> 3) & 3, c = (t2 >> 5) & 15, rest = t2 >> 9;
        int s = rest & 7, tt = rest >> 3;          // tt 0..31
        int u = tt * 16 + c, k = s * 32 + g * 8 + e;
        float v;
        if      (u < 128) v = Wff1[u * 256 + k];
        else if (u < 256) v = Wff2[(u - 128) * 256 + k];
        else if (u < 384) v = Wta [(u - 256) * 256 + k];
        else              v = Wtb [(u - 384) * 256 + k];
        W4f[t2] = f2h_(v);
    }
}

// ---------------------------------------------------------------------------
// Stage A: seq-mean + centered input, 4-period sff row 0 -> x1.
// ---------------------------------------------------------------------------
__global__ __launch_bounds__(256) void sffA_kernel(
    const float* __restrict__ x,
    const float* __restrict__ c3,  const float* __restrict__ l3,
    const float* __restrict__ c6,  const float* __restrict__ l6,
    const float* __restrict__ c12, const float* __restrict__ l12,
    const float* __restrict__ c24, const float* __restrict__ l24,
    float* __restrict__ meanbuf, float* __restrict__ x1)
{
    int bc = blockIdx.x;
    int b = bc / FF, c = bc % FF;
    __shared__ float v[SS], cv[SS], red[256];
    int tid = threadIdx.x;

    float raw = 0.f;
    if (tid < SS) raw = x[(b * FF + c) * SS + tid];
    red[tid] = raw;
    __syncthreads();
    for (int off = 128; off > 0; off >>= 1) {
        if (tid < off) red[tid] += red[tid + off];
        __syncthreads();
    }
    float mv = red[0] * (1.f / SS);
    if (tid == 0) meanbuf[b * FF + c] = mv;
    if (tid < SS) v[tid] = raw - mv;
    __syncthreads();

    const float* cw[4]  = {c3, c6, c12, c24};
    const float* lwv[4] = {l3, l6, l12, l24};
    const int P[4] = {3, 6, 12, 24};
    float acc = 0.f;
    for (int pi = 0; pi < 4; ++pi) {
        int p = P[pi], pad = p >> 1, k = 1 + 2 * pad, seg = SS / p;
        const float* cwp = cw[pi];
        float cc = 0.f;
        if (tid < SS) {
            cc = v[tid];
            for (int j = 0; j < k; ++j) {
                int t = tid + j - pad;
                if (t >= 0 && t < SS) cc += cwp[j] * v[t];
            }
        }
        __syncthreads();
        if (tid < SS) cv[tid] = cc;
        __syncthreads();
        if (tid < SS) {
            int q = tid / p, ph = tid - q * p;
            const float* lwp = lwv[pi];
            float a = 0.f;
            for (int kk = 0; kk < seg; ++kk) a += lwp[q * seg + kk] * cv[kk * p + ph];
            acc += a;
        }
    }
    if (tid < SS) x1[(b * SS + tid) * FF + c] = 0.25f * acc;
}

// ---------------------------------------------------------------------------
// Stage B: sff rows 1,2 on x1[:,:,:3] -> x2, x3.
// ---------------------------------------------------------------------------
__global__ __launch_bounds__(256) void sffB_kernel(
    const float* __restrict__ x1,
    const float* __restrict__ c3,  const float* __restrict__ l3,
    const float* __restrict__ c6,  const float* __restrict__ l6,
    const float* __restrict__ c12, const float* __restrict__ l12,
    const float* __restrict__ c24, const float* __restrict__ l24,
    float* __restrict__ x2, float* __restrict__ x3)
{
    int bc = blockIdx.x;
    int b = bc / 3, c = bc % 3;
    __shared__ float v[SS], cv[SS];
    int tid = threadIdx.x;
    float raw = 0.f;
    if (tid < SS) raw = x1[(b * SS + tid) * FF + c];
    if (tid < SS) v[tid] = raw;
    __syncthreads();

    const float* cw[4]  = {c3, c6, c12, c24};
    const float* lwv[4] = {l3, l6, l12, l24};
    const int P[4] = {3, 6, 12, 24};
    float acc2 = 0.f, acc3 = 0.f;
    for (int pi = 0; pi < 4; ++pi) {
        int p = P[pi], pad = p >> 1, k = 1 + 2 * pad, seg = SS / p;
        for (int row = 1; row <= 2; ++row) {
            const float* cwp = cw[pi] + row * k;
            float cc = 0.f;
            if (tid < SS) {
                cc = v[tid];
                for (int j = 0; j < k; ++j) {
                    int t = tid + j - pad;
                    if (t >= 0 && t < SS) cc += cwp[j] * v[t];
                }
            }
            __syncthreads();
            if (tid < SS) cv[tid] = cc;
            __syncthreads();
            if (tid < SS) {
                int q = tid / p, ph = tid - q * p;
                const float* lwp = lwv[pi] + row * seg * seg;
                float a = 0.f;
                for (int kk = 0; kk < seg; ++kk) a += lwp[q * seg + kk] * cv[kk * p + ph];
                if (row == 1) acc2 += a; else acc3 += a;
            }
        }
    }
    if (tid < SS) {
        x2[(b * SS + tid) * 3 + c] = 0.25f * acc2;
        x3[(b * SS + tid) * 3 + c] = 0.25f * acc3;
    }
}

// ---------------------------------------------------------------------------
// Persistent-weight MFMA scan: 64 blocks x 512 threads, 8 batch rows/block.
// W1 (64 VGPR) + W4 (128 VGPR) persist as B-fragments in registers across
// all 168 steps; W0 (K-padded 160, 80KB fp16) persists in LDS.
// M=16 tile: rows 0..7 real, 8..15 zero. 3 barriers/step.
// GEMM3 tile split per wave: {w, w+8, w+16, w+24} -> each thread's 4 accs are
// ff1/ff2/ta/tb of the SAME unit u = 16w+(lane&15) -> in-register h update.
// ---------------------------------------------------------------------------
__global__ __launch_bounds__(512, 2) void scan_kernel(
    const float* __restrict__ x1g,
    const uint4* __restrict__ W0f, const uint4* __restrict__ W1f, const uint4* __restrict__ W4f,
    const float* __restrict__ bb0, const float* __restrict__ bb1,
    const float* __restrict__ bff1, const float* __restrict__ bff2,
    const float* __restrict__ bta,  const float* __restrict__ btb,
    const float* __restrict__ Wfc,  const float* __restrict__ bfc,
    float* __restrict__ r1g)
{
    const int b0 = blockIdx.x * 8;
    const int tid = threadIdx.x;
    const int w = tid >> 6, lane = tid & 63;
    const int cl = lane & 15, grp = lane >> 4;
    const int fidx = cl * 4 + grp;                 // uint4 index inside a 1KB frag-tile

    __shared__ __align__(16) u16 W0l_s[40960];     // 80KB
    __shared__ __align__(16) u16 zin_s[2560];      // 5KB  [5 ksteps][row16][k32]
    __shared__ __align__(16) u16 z1_s[4096];       // 8KB
    __shared__ __align__(16) u16 z2_s[4096];       // 8KB
    __shared__ __align__(16) float hfs[1024];      // 4KB  [8][128]
    __shared__ __align__(16) float r1s[4032];      // 15.75KB [8][504]
    __shared__ __align__(16) float wfcs[384];

    uint4* W0l4 = (uint4*)W0l_s;
    uint4* zin4 = (uint4*)zin_s;
    uint4* z1_4 = (uint4*)z1_s;
    uint4* z2_4 = (uint4*)z2_s;

    // ---- persistent weight fragments -> registers ----
    f16x8 w1f0[8], w1f1[8], w4f0[8], w4f1[8], w4f2[8], w4f3[8];
    #pragma unroll
    for (int s = 0; s < 8; ++s) {
        w1f0[s] = bc8_(W1f[((w     ) * 8 + s) * 64 + fidx]);
        w1f1[s] = bc8_(W1f[((w +  8) * 8 + s) * 64 + fidx]);
        w4f0[s] = bc8_(W4f[((w     ) * 8 + s) * 64 + fidx]);
        w4f1[s] = bc8_(W4f[((w +  8) * 8 + s) * 64 + fidx]);
        w4f2[s] = bc8_(W4f[((w + 16) * 8 + s) * 64 + fidx]);
        w4f3[s] = bc8_(W4f[((w + 24) * 8 + s) * 64 + fidx]);
    }
    const int u = w * 16 + cl;                     // this thread's unit
    const float bz1a = bb0[u],  bz1b = bb0[128 + u];
    const float bz2a = bb1[u],  bz2b = bb1[128 + u];
    const float bf1r = bff1[u], bf2r = bff2[u];
    const float btar = bta[u],  btbr = btb[u];

    // ---- prologue LDS fills ----
    for (int i = tid; i < 5120; i += 512) W0l4[i] = W0f[i];
    for (int i = tid; i < 320;  i += 512) zin4[i] = make_uint4(0, 0, 0, 0);
    for (int i = tid; i < 512;  i += 512) { z1_4[i] = make_uint4(0,0,0,0); z1_4[i < 0 ? 0 : i] = make_uint4(0,0,0,0); }
    for (int i = tid; i < 512;  i += 512) z1_4[i] = make_uint4(0, 0, 0, 0);
    for (int i = tid; i < 512;  i += 512) z2_4[i] = make_uint4(0, 0, 0, 0);
    if (tid < 384) wfcs[tid] = Wfc[tid];
    __syncthreads();
    if (tid < 96) {                                 // x for s=0 (k=0..11, rows 0..7)
        int r = tid / 12, i = tid % 12;
        zin_s[r * 32 + i] = f2h_(x1g[((b0 + r) * SS + 0) * FF + i]);
    }
    __syncthreads();

    #pragma unroll 1
    for (int s = 0; s < SS; ++s) {
        // prefetch next-step x (used at phase 3)
        float xnext = 0.f;
        if (tid < 96 && s + 1 < SS)
            xnext = x1g[((b0 + tid / 12) * SS + (s + 1)) * FF + (tid % 12)];

        // ---- GEMM1: z1pre = W0 * [x;h]  (A from zin LDS, B from W0 LDS) ----
        f32x4 acc1a = {0.f, 0.f, 0.f, 0.f}, acc1b = {0.f, 0.f, 0.f, 0.f};
        #pragma unroll
        for (int ks = 0; ks < 5; ++ks) {
            f16x8 a = bc8_(zin4[ks * 64 + fidx]);
            acc1a = MFMA16(a, bc8_(W0l4[((w    ) * 5 + ks) * 64 + fidx]), acc1a);
            acc1b = MFMA16(a, bc8_(W0l4[((w + 8) * 5 + ks) * 64 + fidx]), acc1b);
        }

        // ---- readout of step s-1 (overlaps GEMM1; hfs stable until phase 3) ----
        if (s > 0 && tid < 384) {
            int rr = tid >> 4, l = tid & 15;
            int rrow = rr & 7, cc = rr >> 3;
            float4 h0 = *(const float4*)&hfs[rrow * 128 + l * 8];
            float4 h1 = *(const float4*)&hfs[rrow * 128 + l * 8 + 4];
            float4 w0 = *(const float4*)&wfcs[cc * 128 + l * 8];
            float4 w1 = *(const float4*)&wfcs[cc * 128 + l * 8 + 4];
            float val = h0.x*w0.x + h0.y*w0.y + h0.z*w0.z + h0.w*w0.w
                      + h1.x*w1.x + h1.y*w1.y + h1.z*w1.z + h1.w*w1.w;
            val += __shfl_xor(val, 1); val += __shfl_xor(val, 2);
            val += __shfl_xor(val, 4); val += __shfl_xor(val, 8);
            if (l == 0) r1s[rrow * 504 + (s - 1) * 3 + cc] = val + bfc[cc];
        }

        // silu + write z1 (rows 0..7 only)
        if (grp < 2) {
            #pragma unroll
            for (int q = 0; q < 4; ++q) {
                int row = grp * 4 + q;
                int j1 = u, j2 = 128 + u;
                z1_s[(j1 >> 5) * 512 + row * 32 + (j1 & 31)] = f2h_(siluf_(acc1a[q] + bz1a));
                z1_s[(j2 >> 5) * 512 + row * 32 + (j2 & 31)] = f2h_(siluf_(acc1b[q] + bz1b));
            }
        }
        __syncthreads();

        // ---- GEMM2: z2pre = W1 * z1 (B in registers) ----
        f32x4 acc2a = {0.f, 0.f, 0.f, 0.f}, acc2b = {0.f, 0.f, 0.f, 0.f};
        #pragma unroll
        for (int ks = 0; ks < 8; ++ks) {
            f16x8 a = bc8_(z1_4[ks * 64 + fidx]);
            acc2a = MFMA16(a, w1f0[ks], acc2a);
            acc2b = MFMA16(a, w1f1[ks], acc2b);
        }
        if (grp < 2) {
            #pragma unroll
            for (int q = 0; q < 4; ++q) {
                int row = grp * 4 + q;
                int j1 = u, j2 = 128 + u;
                z2_s[(j1 >> 5) * 512 + row * 32 + (j1 & 31)] = f2h_(siluf_(acc2a[q] + bz2a));
                z2_s[(j2 >> 5) * 512 + row * 32 + (j2 & 31)] = f2h_(siluf_(acc2b[q] + bz2b));
            }
        }
        __syncthreads();

        // ---- GEMM3: [ff1;ff2;ta;tb]pre = W4 * z2 (B in registers) ----
        f32x4 acc3a = {0.f,0.f,0.f,0.f}, acc3b = {0.f,0.f,0.f,0.f};
        f32x4 acc3c = {0.f,0.f,0.f,0.f}, acc3d = {0.f,0.f,0.f,0.f};
        #pragma unroll
        for (int ks = 0; ks < 8; ++ks) {
            f16x8 a = bc8_(z2_4[ks * 64 + fidx]);
            acc3a = MFMA16(a, w4f0[ks], acc3a);
            acc3b = MFMA16(a, w4f1[ks], acc3b);
            acc3c = MFMA16(a, w4f2[ks], acc3c);
            acc3d = MFMA16(a, w4f3[ks], acc3d);
        }

        // ---- h update fully in-register; write h -> zin (fp16) + hfs (f32) ----
        if (grp < 2) {
            #pragma unroll
            for (int q = 0; q < 4; ++q) {
                int row = grp * 4 + q;
                float ff1v = tanhf_(acc3a[q] + bf1r);
                float ff2v = tanhf_(acc3b[q] + bf2r);
                float tv   = sigmoidf_((acc3c[q] + btar) + (acc3d[q] + btbr));
                float h    = ff1v + tv * (ff2v - ff1v);
                int k = 12 + u;
                zin_s[(k >> 5) * 512 + row * 32 + (k & 31)] = f2h_(h);
                hfs[row * 128 + u] = h;
            }
        }
        if (tid < 96)
            zin_s[(tid / 12) * 32 + (tid % 12)] = f2h_(xnext);
        __syncthreads();
    }

    // ---- epilogue: readout for s = 167, then write r1 ----
    if (tid < 384) {
        int rr = tid >> 4, l = tid & 15;
        int rrow = rr & 7, cc = rr >> 3;
        float4 h0 = *(const float4*)&hfs[rrow * 128 + l * 8];
        float4 h1 = *(const float4*)&hfs[rrow * 128 + l * 8 + 4];
        float4 w0 = *(const float4*)&wfcs[cc * 128 + l * 8];
        float4 w1 = *(const float4*)&wfcs[cc * 128 + l * 8 + 4];
        float val = h0.x*w0.x + h0.y*w0.y + h0.z*w0.z + h0.w*w0.w
                  + h1.x*w1.x + h1.y*w1.y + h1.z*w1.z + h1.w*w1.w;
        val += __shfl_xor(val, 1); val += __shfl_xor(val, 2);
        val += __shfl_xor(val, 4); val += __shfl_xor(val, 8);
        if (l == 0) r1s[rrow * 504 + 167 * 3 + cc] = val + bfc[cc];
    }
    __syncthreads();
    for (int idx = tid; idx < 4032; idx += 512) {
        int r = idx / 504, rem = idx - r * 504;
        r1g[(b0 + r) * 504 + rem] = r1s[r * 504 + rem];
    }
}

// ---------------------------------------------------------------------------
// Final fits einsum (x3 folded in here now):
// out[b,p,c] = sum_s (r1[b,s,c]+x3[b,s,c]) * Wfits[c,p,s] + mean[b,c] + x2[b,p,c]
// ---------------------------------------------------------------------------
__global__ __launch_bounds__(256) void fits_kernel(
    const float* __restrict__ r1, const float* __restrict__ x3,
    const float* __restrict__ Wfits,
    const float* __restrict__ x2, const float* __restrict__ meanbuf,
    float* __restrict__ out)
{
    int bid = blockIdx.x;
    int bt = bid & 7;
    int rest = bid >> 3;
    int c = rest % 3;
    int pt = rest / 3;
    int b0 = bt * 64, p0 = pt * 28;
    __shared__ float rT[168][65];
    __shared__ float wT[28][168];
    int t = threadIdx.x;
    for (int idx = t; idx < 64 * 168; idx += 256) {
        int b = idx / 168, s = idx - b * 168;
        int gi = ((b0 + b) * 168 + s) * 3 + c;
        rT[s][b] = r1[gi] + x3[gi];
    }
    for (int idx = t; idx < 28 * 168; idx += 256) {
        int p = idx / 168, s = idx - p * 168;
        wT[p][s] = Wfits[(c * 168 + p0 + p) * 168 + s];
    }
    __syncthreads();
    int b = t & 63, pq = t >> 6;
    float acc[7] = {0, 0, 0, 0, 0, 0, 0};
    for (int s = 0; s < 168; ++s) {
        float v = rT[s][b];
        #pragma unroll
        for (int j = 0; j < 7; ++j) acc[j] += v * wT[pq * 7 + j][s];
    }
    float mb = meanbuf[(b0 + b) * 12 + c];
    #pragma unroll
    for (int j = 0; j < 7; ++j) {
        int p = p0 + pq * 7 + j;
        int gi = ((b0 + b) * 168 + p) * 3 + c;
        out[gi] = acc[j] + mb + x2[gi];
    }
}

extern "C" void kernel_launch(void* const* d_in, const int* in_sizes, int n_in,
                              void* d_out, int out_size, void* d_ws, size_t ws_size,
                              hipStream_t stream) {
    const float* x    = (const float*)d_in[0];
    const float* c3   = (const float*)d_in[1];
    const float* l3   = (const float*)d_in[2];
    const float* c6   = (const float*)d_in[3];
    const float* l6   = (const float*)d_in[4];
    const float* c12  = (const float*)d_in[5];
    const float* l12  = (const float*)d_in[6];
    const float* c24  = (const float*)d_in[7];
    const float* l24  = (const float*)d_in[8];
    const float* Wb0  = (const float*)d_in[9];
    const float* bb0  = (const float*)d_in[10];
    const float* Wb1  = (const float*)d_in[11];
    const float* bb1  = (const float*)d_in[12];
    const float* Wff1 = (const float*)d_in[13];
    const float* bff1 = (const float*)d_in[14];
    const float* Wff2 = (const float*)d_in[15];
    const float* bff2 = (const float*)d_in[16];
    const float* Wta  = (const float*)d_in[17];
    const float* bta  = (const float*)d_in[18];
    const float* Wtb  = (const float*)d_in[19];
    const float* btb  = (const float*)d_in[20];
    const float* Wfc  = (const float*)d_in[21];
    const float* bfc  = (const float*)d_in[22];
    const float* Wfits= (const float*)d_in[23];

    float* ws      = (float*)d_ws;
    float* meanbuf = ws;                    // 6144
    float* x1      = meanbuf + 6144;        // 1032192
    float* x2      = x1 + 1032192;          // 258048
    float* x3      = x2 + 258048;           // 258048
    float* r1      = x3 + 258048;           // 258048
    u16*   W0f     = (u16*)(r1 + 258048);   // 40960 u16 (16B aligned)
    u16*   W1f     = W0f + 40960;           // 65536 u16
    u16*   W4f     = W1f + 65536;           // 131072 u16
    float* out     = (float*)d_out;

    prep_kernel<<<(237568 + 255) / 256, 256, 0, stream>>>(Wb0, Wb1, Wff1, Wff2, Wta, Wtb, W0f, W1f, W4f);
    sffA_kernel<<<BB * FF, 256, 0, stream>>>(x, c3, l3, c6, l6, c12, l12, c24, l24, meanbuf, x1);
    sffB_kernel<<<BB * 3, 256, 0, stream>>>(x1, c3, l3, c6, l6, c12, l12, c24, l24, x2, x3);
    scan_kernel<<<BB / 8, 512, 0, stream>>>(x1,
                                            (const uint4*)W0f, (const uint4*)W1f, (const uint4*)W4f,
                                            bb0, bb1, bff1, bff2, bta, btb, Wfc, bfc, r1);
    fits_kernel<<<144, 256, 0, stream>>>(r1, x3, Wfits, x2, meanbuf, out);
}

// Round 4
// 623.547 us; speedup vs baseline: 8.0668x; 1.0303x over previous
//
#include <hip/hip_runtime.h>

#define BB 512
#define SS 168
#define FF 12
#define HH 128
#define UU 256

typedef unsigned short u16;
typedef unsigned int   u32;
typedef _Float16 f16x8 __attribute__((ext_vector_type(8)));
typedef float    f32x4 __attribute__((ext_vector_type(4)));

__device__ __forceinline__ float sigmoidf_(float x){ return __fdividef(1.f, 1.f + __expf(-x)); }
__device__ __forceinline__ float siluf_(float x){ return x * sigmoidf_(x); }
__device__ __forceinline__ float tanhf_(float x){
    float t = __expf(-2.f * fabsf(x));
    float y = __fdividef(1.f - t, 1.f + t);
    return copysignf(y, x);
}
__device__ __forceinline__ u16 f2h_(float v){ return __builtin_bit_cast(u16, (_Float16)v); }
__device__ __forceinline__ f16x8 bc8_(uint4 v){ return __builtin_bit_cast(f16x8, v); }

#define MFMA16(a, b, acc) __builtin_amdgcn_mfma_f32_16x16x32_f16((a), (b), (acc), 0, 0, 0)

// ---------------------------------------------------------------------------
// Weight pre-pack into MFMA B-fragment order, LANE-MAJOR storage (fp16):
// element (col c, k) of tile (t, kstep s) is held by lane L = ((k&31)>>3)*16 + c
// elem e = k&7, stored at flat = (t*NS+s)*512 + L*8 + e.
// Lane L reads its uint4 at (t*NS+s)*64 + L  -> stride-1, conflict-free b128.
// W0f: 16 tiles x 5 ksteps (K=160, zero pad k>=140)  = 40960 u16
// W1f: 16 tiles x 8 ksteps (K=256)                   = 65536 u16
// W4f: 32 tiles x 8 ksteps ([ff1;ff2;ta;tb], K=256)  = 131072 u16
// ---------------------------------------------------------------------------
__global__ void prep_kernel(const float* __restrict__ Wb0, const float* __restrict__ Wb1,
                            const float* __restrict__ Wff1, const float* __restrict__ Wff2,
                            const float* __restrict__ Wta, const float* __restrict__ Wtb,
                            u16* __restrict__ W0f, u16* __restrict__ W1f, u16* __restrict__ W4f)
{
    int t = blockIdx.x * blockDim.x + threadIdx.x;
    if (t < 40960) {
        // flat = ((tt*5+s)*512) + g*128 + c*8 + e
        int e = t & 7, c = (t >> 3) & 15, g = (t >> 7) & 3, rest = t >> 9;
        int s = rest % 5, tt = rest / 5;
        int u = tt * 16 + c, k = s * 32 + g * 8 + e;
        W0f[t] = f2h_((k < 140) ? Wb0[u * 140 + k] : 0.f);
    } else if (t < 40960 + 65536) {
        int t1 = t - 40960;
        int e = t1 & 7, c = (t1 >> 3) & 15, g = (t1 >> 7) & 3, rest = t1 >> 9;
        int s = rest & 7, tt = rest >> 3;
        int u = tt * 16 + c, k = s * 32 + g * 8 + e;
        W1f[t1] = f2h_(Wb1[u * 256 + k]);
    } else if (t < 40960 + 65536 + 131072) {
        int t2 = t - 106496;
        int e = t2 & 7, c = (t2 >> 3) & 15, g = (t2 >> 7) & 3, rest = t2 >> 9;
        int s = rest & 7, tt = rest >> 3;          // tt 0..31
        int u = tt * 16 + c, k = s * 32 + g * 8 + e;
        float v;
        if      (u < 128) v = Wff1[u * 256 + k];
        else if (u < 256) v = Wff2[(u - 128) * 256 + k];
        else if (u < 384) v = Wta [(u - 256) * 256 + k];
        else              v = Wtb [(u - 384) * 256 + k];
        W4f[t2] = f2h_(v);
    }
}

// ---------------------------------------------------------------------------
// Stage A: seq-mean + centered input, 4-period sff row 0 -> x1.
// ---------------------------------------------------------------------------
__global__ __launch_bounds__(256) void sffA_kernel(
    const float* __restrict__ x,
    const float* __restrict__ c3,  const float* __restrict__ l3,
    const float* __restrict__ c6,  const float* __restrict__ l6,
    const float* __restrict__ c12, const float* __restrict__ l12,
    const float* __restrict__ c24, const float* __restrict__ l24,
    float* __restrict__ meanbuf, float* __restrict__ x1)
{
    int bc = blockIdx.x;
    int b = bc / FF, c = bc % FF;
    __shared__ float v[SS], cv[SS], red[256];
    int tid = threadIdx.x;

    float raw = 0.f;
    if (tid < SS) raw = x[(b * FF + c) * SS + tid];
    red[tid] = raw;
    __syncthreads();
    for (int off = 128; off > 0; off >>= 1) {
        if (tid < off) red[tid] += red[tid + off];
        __syncthreads();
    }
    float mv = red[0] * (1.f / SS);
    if (tid == 0) meanbuf[b * FF + c] = mv;
    if (tid < SS) v[tid] = raw - mv;
    __syncthreads();

    const float* cw[4]  = {c3, c6, c12, c24};
    const float* lwv[4] = {l3, l6, l12, l24};
    const int P[4] = {3, 6, 12, 24};
    float acc = 0.f;
    for (int pi = 0; pi < 4; ++pi) {
        int p = P[pi], pad = p >> 1, k = 1 + 2 * pad, seg = SS / p;
        const float* cwp = cw[pi];
        float cc = 0.f;
        if (tid < SS) {
            cc = v[tid];
            for (int j = 0; j < k; ++j) {
                int t = tid + j - pad;
                if (t >= 0 && t < SS) cc += cwp[j] * v[t];
            }
        }
        __syncthreads();
        if (tid < SS) cv[tid] = cc;
        __syncthreads();
        if (tid < SS) {
            int q = tid / p, ph = tid - q * p;
            const float* lwp = lwv[pi];
            float a = 0.f;
            for (int kk = 0; kk < seg; ++kk) a += lwp[q * seg + kk] * cv[kk * p + ph];
            acc += a;
        }
    }
    if (tid < SS) x1[(b * SS + tid) * FF + c] = 0.25f * acc;
}

// ---------------------------------------------------------------------------
// Stage B: sff rows 1,2 on x1[:,:,:3] -> x2, x3.
// ---------------------------------------------------------------------------
__global__ __launch_bounds__(256) void sffB_kernel(
    const float* __restrict__ x1,
    const float* __restrict__ c3,  const float* __restrict__ l3,
    const float* __restrict__ c6,  const float* __restrict__ l6,
    const float* __restrict__ c12, const float* __restrict__ l12,
    const float* __restrict__ c24, const float* __restrict__ l24,
    float* __restrict__ x2, float* __restrict__ x3)
{
    int bc = blockIdx.x;
    int b = bc / 3, c = bc % 3;
    __shared__ float v[SS], cv[SS];
    int tid = threadIdx.x;
    float raw = 0.f;
    if (tid < SS) raw = x1[(b * SS + tid) * FF + c];
    if (tid < SS) v[tid] = raw;
    __syncthreads();

    const float* cw[4]  = {c3, c6, c12, c24};
    const float* lwv[4] = {l3, l6, l12, l24};
    const int P[4] = {3, 6, 12, 24};
    float acc2 = 0.f, acc3 = 0.f;
    for (int pi = 0; pi < 4; ++pi) {
        int p = P[pi], pad = p >> 1, k = 1 + 2 * pad, seg = SS / p;
        for (int row = 1; row <= 2; ++row) {
            const float* cwp = cw[pi] + row * k;
            float cc = 0.f;
            if (tid < SS) {
                cc = v[tid];
                for (int j = 0; j < k; ++j) {
                    int t = tid + j - pad;
                    if (t >= 0 && t < SS) cc += cwp[j] * v[t];
                }
            }
            __syncthreads();
            if (tid < SS) cv[tid] = cc;
            __syncthreads();
            if (tid < SS) {
                int q = tid / p, ph = tid - q * p;
                const float* lwp = lwv[pi] + row * seg * seg;
                float a = 0.f;
                for (int kk = 0; kk < seg; ++kk) a += lwp[q * seg + kk] * cv[kk * p + ph];
                if (row == 1) acc2 += a; else acc3 += a;
            }
        }
    }
    if (tid < SS) {
        x2[(b * SS + tid) * 3 + c] = 0.25f * acc2;
        x3[(b * SS + tid) * 3 + c] = 0.25f * acc3;
    }
}

// ---------------------------------------------------------------------------
// Persistent-weight MFMA scan: 64 blocks x 512 threads, 8 batch rows/block.
// W1+W4 persist as B-fragments in registers; W0 (K=160 padded) in LDS.
// All fragment tiles stored LANE-MAJOR -> conflict-free ds_read_b128.
// r1 written directly to global (no LDS staging).
// ---------------------------------------------------------------------------
__global__ __launch_bounds__(512, 2) void scan_kernel(
    const float* __restrict__ x1g,
    const uint4* __restrict__ W0f, const uint4* __restrict__ W1f, const uint4* __restrict__ W4f,
    const float* __restrict__ bb0, const float* __restrict__ bb1,
    const float* __restrict__ bff1, const float* __restrict__ bff2,
    const float* __restrict__ bta,  const float* __restrict__ btb,
    const float* __restrict__ Wfc,  const float* __restrict__ bfc,
    float* __restrict__ r1g)
{
    const int b0 = blockIdx.x * 8;
    const int tid = threadIdx.x;
    const int w = tid >> 6, lane = tid & 63;
    const int cl = lane & 15, grp = lane >> 4;

    __shared__ __align__(16) u16 W0l_s[40960];     // 80KB
    __shared__ __align__(16) u16 zin_s[2560];      // 5KB  [5 ks][lane][8]
    __shared__ __align__(16) u16 z1_s[4096];       // 8KB  [8 ks][lane][8]
    __shared__ __align__(16) u16 z2_s[4096];       // 8KB
    __shared__ __align__(16) float hfs[1024];      // 4KB  [8][128]
    __shared__ __align__(16) float wfcs[384];
    __shared__ float bfcs[4];

    uint4* W0l4 = (uint4*)W0l_s;
    uint4* zin4 = (uint4*)zin_s;
    uint4* z1_4 = (uint4*)z1_s;
    uint4* z2_4 = (uint4*)z2_s;

    // ---- persistent weight fragments -> registers ----
    f16x8 w1f0[8], w1f1[8], w4f0[8], w4f1[8], w4f2[8], w4f3[8];
    #pragma unroll
    for (int s = 0; s < 8; ++s) {
        w1f0[s] = bc8_(W1f[((w     ) * 8 + s) * 64 + lane]);
        w1f1[s] = bc8_(W1f[((w +  8) * 8 + s) * 64 + lane]);
        w4f0[s] = bc8_(W4f[((w     ) * 8 + s) * 64 + lane]);
        w4f1[s] = bc8_(W4f[((w +  8) * 8 + s) * 64 + lane]);
        w4f2[s] = bc8_(W4f[((w + 16) * 8 + s) * 64 + lane]);
        w4f3[s] = bc8_(W4f[((w + 24) * 8 + s) * 64 + lane]);
    }
    const int u = w * 16 + cl;                     // this thread's unit
    const float bz1a = bb0[u],  bz1b = bb0[128 + u];
    const float bz2a = bb1[u],  bz2b = bb1[128 + u];
    const float bf1r = bff1[u], bf2r = bff2[u];
    const float btar = bta[u],  btbr = btb[u];

    // ---- prologue LDS fills ----
    for (int i = tid; i < 5120; i += 512) W0l4[i] = W0f[i];
    for (int i = tid; i < 320;  i += 512) zin4[i] = make_uint4(0, 0, 0, 0);
    for (int i = tid; i < 512;  i += 512) z1_4[i] = make_uint4(0, 0, 0, 0);
    for (int i = tid; i < 512;  i += 512) z2_4[i] = make_uint4(0, 0, 0, 0);
    if (tid < 384) wfcs[tid] = Wfc[tid];
    if (tid < 3)   bfcs[tid] = bfc[tid];
    __syncthreads();
    if (tid < 96) {                                // x for s=0: k=i<12 -> g=i>>3, e=i&7
        int r = tid / 12, i = tid % 12;
        zin_s[(i >> 3) * 128 + r * 8 + (i & 7)] = f2h_(x1g[((b0 + r) * SS + 0) * FF + i]);
    }
    __syncthreads();

    #pragma unroll 1
    for (int s = 0; s < SS; ++s) {
        // prefetch next-step x (consumed at end of step)
        float xnext = 0.f;
        if (tid < 96 && s + 1 < SS)
            xnext = x1g[((b0 + tid / 12) * SS + (s + 1)) * FF + (tid % 12)];

        // ---- GEMM1: z1pre = W0 * [x;h]  (A from zin LDS, B from W0 LDS) ----
        f32x4 acc1a = {0.f, 0.f, 0.f, 0.f}, acc1b = {0.f, 0.f, 0.f, 0.f};
        #pragma unroll
        for (int ks = 0; ks < 5; ++ks) {
            f16x8 a = bc8_(zin4[ks * 64 + lane]);
            acc1a = MFMA16(a, bc8_(W0l4[((w    ) * 5 + ks) * 64 + lane]), acc1a);
            acc1b = MFMA16(a, bc8_(W0l4[((w + 8) * 5 + ks) * 64 + lane]), acc1b);
        }

        // ---- readout of step s-1 (overlaps GEMM1; hfs stable until C3) ----
        if (s > 0 && tid < 384) {
            int rr = tid >> 4, l = tid & 15;
            int rrow = rr & 7, cc = rr >> 3;
            float4 h0 = *(const float4*)&hfs[rrow * 128 + l * 8];
            float4 h1 = *(const float4*)&hfs[rrow * 128 + l * 8 + 4];
            float4 w0 = *(const float4*)&wfcs[cc * 128 + l * 8];
            float4 w1 = *(const float4*)&wfcs[cc * 128 + l * 8 + 4];
            float val = h0.x*w0.x + h0.y*w0.y + h0.z*w0.z + h0.w*w0.w
                      + h1.x*w1.x + h1.y*w1.y + h1.z*w1.z + h1.w*w1.w;
            val += __shfl_xor(val, 1); val += __shfl_xor(val, 2);
            val += __shfl_xor(val, 4); val += __shfl_xor(val, 8);
            if (l == 0)
                r1g[(b0 + rrow) * 504 + (s - 1) * 3 + cc] = val + bfcs[cc];
        }

        // silu + write z1 (rows 0..7 only; element (row, j) -> lane-major slot)
        if (grp < 2) {
            #pragma unroll
            for (int q = 0; q < 4; ++q) {
                int row = grp * 4 + q;
                int j1 = u, j2 = 128 + u;
                z1_s[(j1 >> 5) * 512 + ((j1 & 31) >> 3) * 128 + row * 8 + (j1 & 7)] = f2h_(siluf_(acc1a[q] + bz1a));
                z1_s[(j2 >> 5) * 512 + ((j2 & 31) >> 3) * 128 + row * 8 + (j2 & 7)] = f2h_(siluf_(acc1b[q] + bz1b));
            }
        }
        __syncthreads();

        // ---- GEMM2: z2pre = W1 * z1 (B in registers) ----
        f32x4 acc2a = {0.f, 0.f, 0.f, 0.f}, acc2b = {0.f, 0.f, 0.f, 0.f};
        #pragma unroll
        for (int ks = 0; ks < 8; ++ks) {
            f16x8 a = bc8_(z1_4[ks * 64 + lane]);
            acc2a = MFMA16(a, w1f0[ks], acc2a);
            acc2b = MFMA16(a, w1f1[ks], acc2b);
        }
        if (grp < 2) {
            #pragma unroll
            for (int q = 0; q < 4; ++q) {
                int row = grp * 4 + q;
                int j1 = u, j2 = 128 + u;
                z2_s[(j1 >> 5) * 512 + ((j1 & 31) >> 3) * 128 + row * 8 + (j1 & 7)] = f2h_(siluf_(acc2a[q] + bz2a));
                z2_s[(j2 >> 5) * 512 + ((j2 & 31) >> 3) * 128 + row * 8 + (j2 & 7)] = f2h_(siluf_(acc2b[q] + bz2b));
            }
        }
        __syncthreads();

        // ---- GEMM3: [ff1;ff2;ta;tb]pre = W4 * z2 (B in registers) ----
        f32x4 acc3a = {0.f,0.f,0.f,0.f}, acc3b = {0.f,0.f,0.f,0.f};
        f32x4 acc3c = {0.f,0.f,0.f,0.f}, acc3d = {0.f,0.f,0.f,0.f};
        #pragma unroll
        for (int ks = 0; ks < 8; ++ks) {
            f16x8 a = bc8_(z2_4[ks * 64 + lane]);
            acc3a = MFMA16(a, w4f0[ks], acc3a);
            acc3b = MFMA16(a, w4f1[ks], acc3b);
            acc3c = MFMA16(a, w4f2[ks], acc3c);
            acc3d = MFMA16(a, w4f3[ks], acc3d);
        }

        // ---- h update fully in-register; write h -> zin (fp16) + hfs (f32) ----
        if (grp < 2) {
            #pragma unroll
            for (int q = 0; q < 4; ++q) {
                int row = grp * 4 + q;
                float ff1v = tanhf_(acc3a[q] + bf1r);
                float ff2v = tanhf_(acc3b[q] + bf2r);
                float tv   = sigmoidf_((acc3c[q] + btar) + (acc3d[q] + btbr));
                float h    = ff1v + tv * (ff2v - ff1v);
                int k = 12 + u;
                zin_s[(k >> 5) * 512 + ((k & 31) >> 3) * 128 + row * 8 + (k & 7)] = f2h_(h);
                hfs[row * 128 + u] = h;
            }
        }
        if (tid < 96) {
            int r = tid / 12, i = tid % 12;
            zin_s[(i >> 3) * 128 + r * 8 + (i & 7)] = f2h_(xnext);
        }
        __syncthreads();
    }

    // ---- epilogue: readout for s = 167 ----
    if (tid < 384) {
        int rr = tid >> 4, l = tid & 15;
        int rrow = rr & 7, cc = rr >> 3;
        float4 h0 = *(const float4*)&hfs[rrow * 128 + l * 8];
        float4 h1 = *(const float4*)&hfs[rrow * 128 + l * 8 + 4];
        float4 w0 = *(const float4*)&wfcs[cc * 128 + l * 8];
        float4 w1 = *(const float4*)&wfcs[cc * 128 + l * 8 + 4];
        float val = h0.x*w0.x + h0.y*w0.y + h0.z*w0.z + h0.w*w0.w
                  + h1.x*w1.x + h1.y*w1.y + h1.z*w1.z + h1.w*w1.w;
        val += __shfl_xor(val, 1); val += __shfl_xor(val, 2);
        val += __shfl_xor(val, 4); val += __shfl_xor(val, 8);
        if (l == 0)
            r1g[(b0 + rrow) * 504 + 167 * 3 + cc] = val + bfcs[cc];
    }
}

// ---------------------------------------------------------------------------
// Final fits einsum (x3 folded in):
// out[b,p,c] = sum_s (r1[b,s,c]+x3[b,s,c]) * Wfits[c,p,s] + mean[b,c] + x2[b,p,c]
// ---------------------------------------------------------------------------
__global__ __launch_bounds__(256) void fits_kernel(
    const float* __restrict__ r1, const float* __restrict__ x3,
    const float* __restrict__ Wfits,
    const float* __restrict__ x2, const float* __restrict__ meanbuf,
    float* __restrict__ out)
{
    int bid = blockIdx.x;
    int bt = bid & 7;
    int rest = bid >> 3;
    int c = rest % 3;
    int pt = rest / 3;
    int b0 = bt * 64, p0 = pt * 28;
    __shared__ float rT[168][65];
    __shared__ float wT[28][168];
    int t = threadIdx.x;
    for (int idx = t; idx < 64 * 168; idx += 256) {
        int b = idx / 168, s = idx - b * 168;
        int gi = ((b0 + b) * 168 + s) * 3 + c;
        rT[s][b] = r1[gi] + x3[gi];
    }
    for (int idx = t; idx < 28 * 168; idx += 256) {
        int p = idx / 168, s = idx - p * 168;
        wT[p][s] = Wfits[(c * 168 + p0 + p) * 168 + s];
    }
    __syncthreads();
    int b = t & 63, pq = t >> 6;
    float acc[7] = {0, 0, 0, 0, 0, 0, 0};
    for (int s = 0; s < 168; ++s) {
        float v = rT[s][b];
        #pragma unroll
        for (int j = 0; j < 7; ++j) acc[j] += v * wT[pq * 7 + j][s];
    }
    float mb = meanbuf[(b0 + b) * 12 + c];
    #pragma unroll
    for (int j = 0; j < 7; ++j) {
        int p = p0 + pq * 7 + j;
        int gi = ((b0 + b) * 168 + p) * 3 + c;
        out[gi] = acc[j] + mb + x2[gi];
    }
}

extern "C" void kernel_launch(void* const* d_in, const int* in_sizes, int n_in,
                              void* d_out, int out_size, void* d_ws, size_t ws_size,
                              hipStream_t stream) {
    const float* x    = (const float*)d_in[0];
    const float* c3   = (const float*)d_in[1];
    const float* l3   = (const float*)d_in[2];
    const float* c6   = (const float*)d_in[3];
    const float* l6   = (const float*)d_in[4];
    const float* c12  = (const float*)d_in[5];
    const float* l12  = (const float*)d_in[6];
    const float* c24  = (const float*)d_in[7];
    const float* l24  = (const float*)d_in[8];
    const float* Wb0  = (const float*)d_in[9];
    const float* bb0  = (const float*)d_in[10];
    const float* Wb1  = (const float*)d_in[11];
    const float* bb1  = (const float*)d_in[12];
    const float* Wff1 = (const float*)d_in[13];
    const float* bff1 = (const float*)d_in[14];
    const float* Wff2 = (const float*)d_in[15];
    const float* bff2 = (const float*)d_in[16];
    const float* Wta  = (const float*)d_in[17];
    const float* bta  = (const float*)d_in[18];
    const float* Wtb  = (const float*)d_in[19];
    const float* btb  = (const float*)d_in[20];
    const float* Wfc  = (const float*)d_in[21];
    const float* bfc  = (const float*)d_in[22];
    const float* Wfits= (const float*)d_in[23];

    float* ws      = (float*)d_ws;
    float* meanbuf = ws;                    // 6144
    float* x1      = meanbuf + 6144;        // 1032192
    float* x2      = x1 + 1032192;          // 258048
    float* x3      = x2 + 258048;           // 258048
    float* r1      = x3 + 258048;           // 258048
    u16*   W0f     = (u16*)(r1 + 258048);   // 40960 u16 (16B aligned)
    u16*   W1f     = W0f + 40960;           // 65536 u16
    u16*   W4f     = W1f + 65536;           // 131072 u16
    float* out     = (float*)d_out;

    prep_kernel<<<(237568 + 255) / 256, 256, 0, stream>>>(Wb0, Wb1, Wff1, Wff2, Wta, Wtb, W0f, W1f, W4f);
    sffA_kernel<<<BB * FF, 256, 0, stream>>>(x, c3, l3, c6, l6, c12, l12, c24, l24, meanbuf, x1);
    sffB_kernel<<<BB * 3, 256, 0, stream>>>(x1, c3, l3, c6, l6, c12, l12, c24, l24, x2, x3);
    scan_kernel<<<BB / 8, 512, 0, stream>>>(x1,
                                            (const uint4*)W0f, (const uint4*)W1f, (const uint4*)W4f,
                                            bb0, bb1, bff1, bff2, bta, btb, Wfc, bfc, r1);
    fits_kernel<<<144, 256, 0, stream>>>(r1, x3, Wfits, x2, meanbuf, out);
}

// Round 5
// 407.648 us; speedup vs baseline: 12.3391x; 1.5296x over previous
//
#include <hip/hip_runtime.h>

#define BB 512
#define SS 168
#define FF 12
#define HH 128
#define UU 256

typedef unsigned short u16;
typedef unsigned int   u32;
typedef _Float16 f16x8 __attribute__((ext_vector_type(8)));
typedef float    f32x4 __attribute__((ext_vector_type(4)));

__device__ __forceinline__ float sigmoidf_(float x){ return __fdividef(1.f, 1.f + __expf(-x)); }
__device__ __forceinline__ float siluf_(float x){ return x * sigmoidf_(x); }
__device__ __forceinline__ float tanhf_(float x){
    float t = __expf(-2.f * fabsf(x));
    float y = __fdividef(1.f - t, 1.f + t);
    return copysignf(y, x);
}
__device__ __forceinline__ u16 f2h_(float v){ return __builtin_bit_cast(u16, (_Float16)v); }
__device__ __forceinline__ f16x8 bc8_(uint4 v){ return __builtin_bit_cast(f16x8, v); }
// A/B fragment slot for element (row/col, k): lane-major, conflict-free b128 reads
__device__ __forceinline__ int aslot_(int row, int k){
    return (k >> 5) * 512 + ((k & 31) >> 3) * 128 + row * 8 + (k & 7);
}

#define MFMA16(a, b, acc) __builtin_amdgcn_mfma_f32_16x16x32_f16((a), (b), (acc), 0, 0, 0)

// ---------------------------------------------------------------------------
// Weight pre-pack, lane-major B-fragments (fp16):
// W0f: 17 tiles x 5 ks (K=160; pad k>=140). tiles 0..15 = Wb0 cols; tile 16 =
//      readout tile: B[k][c] = Wfc[c][k-12] for 12<=k<140, c<3, else 0.
// W1f: 16 tiles x 8 ks (K=256) = Wb1.
// W4f: 24 tiles x 8 ks: tiles 0..7 ff1, 8..15 ff2, 16..23 (Wta+Wtb).
// ---------------------------------------------------------------------------
__global__ void prep_kernel(const float* __restrict__ Wb0, const float* __restrict__ Wb1,
                            const float* __restrict__ Wff1, const float* __restrict__ Wff2,
                            const float* __restrict__ Wta, const float* __restrict__ Wtb,
                            const float* __restrict__ Wfc,
                            u16* __restrict__ W0f, u16* __restrict__ W1f, u16* __restrict__ W4f)
{
    int t = blockIdx.x * blockDim.x + threadIdx.x;
    if (t < 43520) {
        int e = t & 7, c = (t >> 3) & 15, g = (t >> 7) & 3, rest = t >> 9;
        int s = rest % 5, tt = rest / 5;
        int k = s * 32 + g * 8 + e;
        float v;
        if (tt < 16) { int u = tt * 16 + c; v = (k < 140) ? Wb0[u * 140 + k] : 0.f; }
        else         { v = (c < 3 && k >= 12 && k < 140) ? Wfc[c * 128 + (k - 12)] : 0.f; }
        W0f[t] = f2h_(v);
    } else if (t < 43520 + 65536) {
        int t1 = t - 43520;
        int e = t1 & 7, c = (t1 >> 3) & 15, g = (t1 >> 7) & 3, rest = t1 >> 9;
        int s = rest & 7, tt = rest >> 3;
        int u = tt * 16 + c, k = s * 32 + g * 8 + e;
        W1f[t1] = f2h_(Wb1[u * 256 + k]);
    } else if (t < 43520 + 65536 + 98304) {
        int t2 = t - 109056;
        int e = t2 & 7, c = (t2 >> 3) & 15, g = (t2 >> 7) & 3, rest = t2 >> 9;
        int s = rest & 7, tt = rest >> 3;          // 0..23
        int u = (tt & 7) * 16 + c, k = s * 32 + g * 8 + e;
        float v;
        if      (tt < 8)  v = Wff1[u * 256 + k];
        else if (tt < 16) v = Wff2[u * 256 + k];
        else              v = Wta[u * 256 + k] + Wtb[u * 256 + k];
        W4f[t2] = f2h_(v);
    }
}

// ---------------------------------------------------------------------------
// Stage A: seq-mean + centered input, 4-period sff row 0 -> x1.
// ---------------------------------------------------------------------------
__global__ __launch_bounds__(256) void sffA_kernel(
    const float* __restrict__ x,
    const float* __restrict__ c3,  const float* __restrict__ l3,
    const float* __restrict__ c6,  const float* __restrict__ l6,
    const float* __restrict__ c12, const float* __restrict__ l12,
    const float* __restrict__ c24, const float* __restrict__ l24,
    float* __restrict__ meanbuf, float* __restrict__ x1)
{
    int bc = blockIdx.x;
    int b = bc / FF, c = bc % FF;
    __shared__ float v[SS], cv[SS], red[256];
    int tid = threadIdx.x;

    float raw = 0.f;
    if (tid < SS) raw = x[(b * FF + c) * SS + tid];
    red[tid] = raw;
    __syncthreads();
    for (int off = 128; off > 0; off >>= 1) {
        if (tid < off) red[tid] += red[tid + off];
        __syncthreads();
    }
    float mv = red[0] * (1.f / SS);
    if (tid == 0) meanbuf[b * FF + c] = mv;
    if (tid < SS) v[tid] = raw - mv;
    __syncthreads();

    const float* cw[4]  = {c3, c6, c12, c24};
    const float* lwv[4] = {l3, l6, l12, l24};
    const int P[4] = {3, 6, 12, 24};
    float acc = 0.f;
    for (int pi = 0; pi < 4; ++pi) {
        int p = P[pi], pad = p >> 1, k = 1 + 2 * pad, seg = SS / p;
        const float* cwp = cw[pi];
        float cc = 0.f;
        if (tid < SS) {
            cc = v[tid];
            for (int j = 0; j < k; ++j) {
                int t = tid + j - pad;
                if (t >= 0 && t < SS) cc += cwp[j] * v[t];
            }
        }
        __syncthreads();
        if (tid < SS) cv[tid] = cc;
        __syncthreads();
        if (tid < SS) {
            int q = tid / p, ph = tid - q * p;
            const float* lwp = lwv[pi];
            float a = 0.f;
            for (int kk = 0; kk < seg; ++kk) a += lwp[q * seg + kk] * cv[kk * p + ph];
            acc += a;
        }
    }
    if (tid < SS) x1[(b * SS + tid) * FF + c] = 0.25f * acc;
}

// ---------------------------------------------------------------------------
// Stage B: sff rows 1,2 on x1[:,:,:3] -> x2, x3.
// ---------------------------------------------------------------------------
__global__ __launch_bounds__(256) void sffB_kernel(
    const float* __restrict__ x1,
    const float* __restrict__ c3,  const float* __restrict__ l3,
    const float* __restrict__ c6,  const float* __restrict__ l6,
    const float* __restrict__ c12, const float* __restrict__ l12,
    const float* __restrict__ c24, const float* __restrict__ l24,
    float* __restrict__ x2, float* __restrict__ x3)
{
    int bc = blockIdx.x;
    int b = bc / 3, c = bc % 3;
    __shared__ float v[SS], cv[SS];
    int tid = threadIdx.x;
    float raw = 0.f;
    if (tid < SS) raw = x1[(b * SS + tid) * FF + c];
    if (tid < SS) v[tid] = raw;
    __syncthreads();

    const float* cw[4]  = {c3, c6, c12, c24};
    const float* lwv[4] = {l3, l6, l12, l24};
    const int P[4] = {3, 6, 12, 24};
    float acc2 = 0.f, acc3 = 0.f;
    for (int pi = 0; pi < 4; ++pi) {
        int p = P[pi], pad = p >> 1, k = 1 + 2 * pad, seg = SS / p;
        for (int row = 1; row <= 2; ++row) {
            const float* cwp = cw[pi] + row * k;
            float cc = 0.f;
            if (tid < SS) {
                cc = v[tid];
                for (int j = 0; j < k; ++j) {
                    int t = tid + j - pad;
                    if (t >= 0 && t < SS) cc += cwp[j] * v[t];
                }
            }
            __syncthreads();
            if (tid < SS) cv[tid] = cc;
            __syncthreads();
            if (tid < SS) {
                int q = tid / p, ph = tid - q * p;
                const float* lwp = lwv[pi] + row * seg * seg;
                float a = 0.f;
                for (int kk = 0; kk < seg; ++kk) a += lwp[q * seg + kk] * cv[kk * p + ph];
                if (row == 1) acc2 += a; else acc3 += a;
            }
        }
    }
    if (tid < SS) {
        x2[(b * SS + tid) * 3 + c] = 0.25f * acc2;
        x3[(b * SS + tid) * 3 + c] = 0.25f * acc3;
    }
}

// ---------------------------------------------------------------------------
// Persistent-weight MFMA scan: 64 blocks x 512 threads, 8 batch rows/block.
// Batch row br -> tile row (br>>1)*4+(br&1): every lane owns 2 real rows
// (acc regs [0],[1]) -> activations use all 64 lanes. Readout = extra MFMA
// B-tile (tile 16 of W0) computed by wave 0 from zin's h-region.
// Zero in-loop global traffic: x1 slice pre-staged in LDS, r1 staged in LDS.
// ---------------------------------------------------------------------------
__global__ __launch_bounds__(512, 2) void scan_kernel(
    const float* __restrict__ x1g,
    const uint4* __restrict__ W0f, const uint4* __restrict__ W1f, const uint4* __restrict__ W4f,
    const float* __restrict__ bb0, const float* __restrict__ bb1,
    const float* __restrict__ bff1, const float* __restrict__ bff2,
    const float* __restrict__ bta,  const float* __restrict__ btb,
    const float* __restrict__ bfc,
    float* __restrict__ r1g)
{
    const int b0 = blockIdx.x * 8;
    const int tid = threadIdx.x;
    const int w = tid >> 6, lane = tid & 63;
    const int cl = lane & 15, grp = lane >> 4;

    __shared__ __align__(16) u16 W0l_s[43520];     // 85KB  (17 tiles x 5 ks)
    __shared__ __align__(16) u16 xh[16128];        // 31.5KB [s][8 rows][12] fp16
    __shared__ __align__(16) u16 zin_s[2560];      // 5KB
    __shared__ __align__(16) u16 z1_s[4096];       // 8KB
    __shared__ __align__(16) u16 z2_s[4096];       // 8KB
    __shared__ __align__(16) float r1s[4032];      // 15.75KB [8][504]
    __shared__ float bfcs[4];

    uint4* W0l4 = (uint4*)W0l_s;
    uint4* zin4 = (uint4*)zin_s;
    uint4* z1_4 = (uint4*)z1_s;
    uint4* z2_4 = (uint4*)z2_s;

    // ---- persistent weight fragments -> registers (W1: 2 tiles, W4: 3 tiles) ----
    f16x8 w1f0[8], w1f1[8], w4a[8], w4b[8], w4c[8];
    #pragma unroll
    for (int s = 0; s < 8; ++s) {
        w1f0[s] = bc8_(W1f[((w     ) * 8 + s) * 64 + lane]);
        w1f1[s] = bc8_(W1f[((w +  8) * 8 + s) * 64 + lane]);
        w4a[s]  = bc8_(W4f[((w     ) * 8 + s) * 64 + lane]);
        w4b[s]  = bc8_(W4f[((w +  8) * 8 + s) * 64 + lane]);
        w4c[s]  = bc8_(W4f[((w + 16) * 8 + s) * 64 + lane]);
    }
    const int u = w * 16 + cl;                     // this thread's unit
    const float bz1a = bb0[u],  bz1b = bb0[128 + u];
    const float bz2a = bb1[u],  bz2b = bb1[128 + u];
    const float bf1r = bff1[u], bf2r = bff2[u];
    const float btsr = bta[u] + btb[u];

    // ---- prologue LDS fills ----
    for (int i = tid; i < 5440; i += 512) W0l4[i] = W0f[i];
    for (int i = tid; i < 16128; i += 512) {
        int s = i / 96, rem = i - s * 96, r = rem / 12, ii = rem - r * 12;
        xh[i] = f2h_(x1g[((b0 + r) * SS + s) * FF + ii]);
    }
    for (int i = tid; i < 320; i += 512) zin4[i] = make_uint4(0, 0, 0, 0);
    for (int i = tid; i < 512; i += 512) z1_4[i] = make_uint4(0, 0, 0, 0);
    for (int i = tid; i < 512; i += 512) z2_4[i] = make_uint4(0, 0, 0, 0);
    if (tid < 3) bfcs[tid] = bfc[tid];
    __syncthreads();
    if (tid < 96) {                                 // x for s=0
        int r = tid / 12, i = tid % 12;
        int trow = (r >> 1) * 4 + (r & 1);
        zin_s[aslot_(trow, i)] = xh[tid];
    }
    __syncthreads();

    #pragma unroll 1
    for (int s = 0; s < SS; ++s) {
        // ---- Phase A: GEMM1 z1pre = W0 * [x(s); h(s-1)] ----
        f32x4 a1a0 = {0.f,0.f,0.f,0.f}, a1a1 = {0.f,0.f,0.f,0.f};
        f32x4 a1b0 = {0.f,0.f,0.f,0.f}, a1b1 = {0.f,0.f,0.f,0.f};
        #pragma unroll
        for (int ks = 0; ks < 5; ++ks) {
            f16x8 av  = bc8_(zin4[ks * 64 + lane]);
            f16x8 b0v = bc8_(W0l4[((w    ) * 5 + ks) * 64 + lane]);
            f16x8 b1v = bc8_(W0l4[((w + 8) * 5 + ks) * 64 + lane]);
            if (ks & 1) { a1a1 = MFMA16(av, b0v, a1a1); a1b1 = MFMA16(av, b1v, a1b1); }
            else        { a1a0 = MFMA16(av, b0v, a1a0); a1b0 = MFMA16(av, b1v, a1b0); }
        }

        // readout of step s-1 via MFMA tile 16 (wave 0 only; h(s-1) is in zin)
        if (w == 0 && s > 0) {
            f32x4 accr = {0.f, 0.f, 0.f, 0.f};
            #pragma unroll
            for (int ks = 0; ks < 5; ++ks)
                accr = MFMA16(bc8_(zin4[ks * 64 + lane]),
                              bc8_(W0l4[(80 + ks) * 64 + lane]), accr);
            if (cl < 3) {
                r1s[(2 * grp    ) * 504 + (s - 1) * 3 + cl] = accr[0] + bfcs[cl];
                r1s[(2 * grp + 1) * 504 + (s - 1) * 3 + cl] = accr[1] + bfcs[cl];
            }
        }

        // silu + write z1 (2 real rows per lane)
        {
            int t0r = grp * 4, t1r = grp * 4 + 1;
            z1_s[aslot_(t0r, u)]       = f2h_(siluf_(a1a0[0] + a1a1[0] + bz1a));
            z1_s[aslot_(t1r, u)]       = f2h_(siluf_(a1a0[1] + a1a1[1] + bz1a));
            z1_s[aslot_(t0r, 128 + u)] = f2h_(siluf_(a1b0[0] + a1b1[0] + bz1b));
            z1_s[aslot_(t1r, 128 + u)] = f2h_(siluf_(a1b0[1] + a1b1[1] + bz1b));
        }
        __syncthreads();

        // ---- Phase B: GEMM2 z2pre = W1 * z1 (B in registers) ----
        f32x4 a2a0 = {0.f,0.f,0.f,0.f}, a2a1 = {0.f,0.f,0.f,0.f};
        f32x4 a2b0 = {0.f,0.f,0.f,0.f}, a2b1 = {0.f,0.f,0.f,0.f};
        #pragma unroll
        for (int ks = 0; ks < 8; ++ks) {
            f16x8 av = bc8_(z1_4[ks * 64 + lane]);
            if (ks & 1) { a2a1 = MFMA16(av, w1f0[ks], a2a1); a2b1 = MFMA16(av, w1f1[ks], a2b1); }
            else        { a2a0 = MFMA16(av, w1f0[ks], a2a0); a2b0 = MFMA16(av, w1f1[ks], a2b0); }
        }
        {
            int t0r = grp * 4, t1r = grp * 4 + 1;
            z2_s[aslot_(t0r, u)]       = f2h_(siluf_(a2a0[0] + a2a1[0] + bz2a));
            z2_s[aslot_(t1r, u)]       = f2h_(siluf_(a2a0[1] + a2a1[1] + bz2a));
            z2_s[aslot_(t0r, 128 + u)] = f2h_(siluf_(a2b0[0] + a2b1[0] + bz2b));
            z2_s[aslot_(t1r, 128 + u)] = f2h_(siluf_(a2b0[1] + a2b1[1] + bz2b));
        }
        __syncthreads();

        // ---- Phase C: GEMM3 [ff1; ff2; tsum]pre = W4 * z2 (B in registers) ----
        f32x4 c3a0 = {0.f,0.f,0.f,0.f}, c3a1 = {0.f,0.f,0.f,0.f};
        f32x4 c3b0 = {0.f,0.f,0.f,0.f}, c3b1 = {0.f,0.f,0.f,0.f};
        f32x4 c3c0 = {0.f,0.f,0.f,0.f}, c3c1 = {0.f,0.f,0.f,0.f};
        #pragma unroll
        for (int ks = 0; ks < 8; ++ks) {
            f16x8 av = bc8_(z2_4[ks * 64 + lane]);
            if (ks & 1) {
                c3a1 = MFMA16(av, w4a[ks], c3a1);
                c3b1 = MFMA16(av, w4b[ks], c3b1);
                c3c1 = MFMA16(av, w4c[ks], c3c1);
            } else {
                c3a0 = MFMA16(av, w4a[ks], c3a0);
                c3b0 = MFMA16(av, w4b[ks], c3b0);
                c3c0 = MFMA16(av, w4c[ks], c3c0);
            }
        }

        // h update (2 real rows per lane, all lanes busy)
        #pragma unroll
        for (int q = 0; q < 2; ++q) {
            float ff1v = tanhf_(c3a0[q] + c3a1[q] + bf1r);
            float ff2v = tanhf_(c3b0[q] + c3b1[q] + bf2r);
            float tv   = sigmoidf_(c3c0[q] + c3c1[q] + btsr);
            float h    = ff1v + tv * (ff2v - ff1v);
            zin_s[aslot_(grp * 4 + q, 12 + u)] = f2h_(h);
        }
        if (tid < 96 && s + 1 < SS) {
            int r = tid / 12, i = tid % 12;
            int trow = (r >> 1) * 4 + (r & 1);
            zin_s[aslot_(trow, i)] = xh[(s + 1) * 96 + tid];
        }
        __syncthreads();
    }

    // ---- epilogue: readout for s = 167 (h(167) is in zin) ----
    if (w == 0) {
        f32x4 accr = {0.f, 0.f, 0.f, 0.f};
        #pragma unroll
        for (int ks = 0; ks < 5; ++ks)
            accr = MFMA16(bc8_(zin4[ks * 64 + lane]),
                          bc8_(W0l4[(80 + ks) * 64 + lane]), accr);
        if (cl < 3) {
            r1s[(2 * grp    ) * 504 + 167 * 3 + cl] = accr[0] + bfcs[cl];
            r1s[(2 * grp + 1) * 504 + 167 * 3 + cl] = accr[1] + bfcs[cl];
        }
    }
    __syncthreads();
    for (int idx = tid; idx < 4032; idx += 512) {
        int r = idx / 504, rem = idx - r * 504;
        r1g[(b0 + r) * 504 + rem] = r1s[r * 504 + rem];
    }
}

// ---------------------------------------------------------------------------
// Final fits einsum (x3 folded in):
// out[b,p,c] = sum_s (r1[b,s,c]+x3[b,s,c]) * Wfits[c,p,s] + mean[b,c] + x2[b,p,c]
// ---------------------------------------------------------------------------
__global__ __launch_bounds__(256) void fits_kernel(
    const float* __restrict__ r1, const float* __restrict__ x3,
    const float* __restrict__ Wfits,
    const float* __restrict__ x2, const float* __restrict__ meanbuf,
    float* __restrict__ out)
{
    int bid = blockIdx.x;
    int bt = bid & 7;
    int rest = bid >> 3;
    int c = rest % 3;
    int pt = rest / 3;
    int b0 = bt * 64, p0 = pt * 28;
    __shared__ float rT[168][65];
    __shared__ float wT[28][168];
    int t = threadIdx.x;
    for (int idx = t; idx < 64 * 168; idx += 256) {
        int b = idx / 168, s = idx - b * 168;
        int gi = ((b0 + b) * 168 + s) * 3 + c;
        rT[s][b] = r1[gi] + x3[gi];
    }
    for (int idx = t; idx < 28 * 168; idx += 256) {
        int p = idx / 168, s = idx - p * 168;
        wT[p][s] = Wfits[(c * 168 + p0 + p) * 168 + s];
    }
    __syncthreads();
    int b = t & 63, pq = t >> 6;
    float acc[7] = {0, 0, 0, 0, 0, 0, 0};
    for (int s = 0; s < 168; ++s) {
        float v = rT[s][b];
        #pragma unroll
        for (int j = 0; j < 7; ++j) acc[j] += v * wT[pq * 7 + j][s];
    }
    float mb = meanbuf[(b0 + b) * 12 + c];
    #pragma unroll
    for (int j = 0; j < 7; ++j) {
        int p = p0 + pq * 7 + j;
        int gi = ((b0 + b) * 168 + p) * 3 + c;
        out[gi] = acc[j] + mb + x2[gi];
    }
}

extern "C" void kernel_launch(void* const* d_in, const int* in_sizes, int n_in,
                              void* d_out, int out_size, void* d_ws, size_t ws_size,
                              hipStream_t stream) {
    const float* x    = (const float*)d_in[0];
    const float* c3   = (const float*)d_in[1];
    const float* l3   = (const float*)d_in[2];
    const float* c6   = (const float*)d_in[3];
    const float* l6   = (const float*)d_in[4];
    const float* c12  = (const float*)d_in[5];
    const float* l12  = (const float*)d_in[6];
    const float* c24  = (const float*)d_in[7];
    const float* l24  = (const float*)d_in[8];
    const float* Wb0  = (const float*)d_in[9];
    const float* bb0  = (const float*)d_in[10];
    const float* Wb1  = (const float*)d_in[11];
    const float* bb1  = (const float*)d_in[12];
    const float* Wff1 = (const float*)d_in[13];
    const float* bff1 = (const float*)d_in[14];
    const float* Wff2 = (const float*)d_in[15];
    const float* bff2 = (const float*)d_in[16];
    const float* Wta  = (const float*)d_in[17];
    const float* bta  = (const float*)d_in[18];
    const float* Wtb  = (const float*)d_in[19];
    const float* btb  = (const float*)d_in[20];
    const float* Wfc  = (const float*)d_in[21];
    const float* bfc  = (const float*)d_in[22];
    const float* Wfits= (const float*)d_in[23];

    float* ws      = (float*)d_ws;
    float* meanbuf = ws;                    // 6144
    float* x1      = meanbuf + 6144;        // 1032192
    float* x2      = x1 + 1032192;          // 258048
    float* x3      = x2 + 258048;           // 258048
    float* r1      = x3 + 258048;           // 258048
    u16*   W0f     = (u16*)(r1 + 258048);   // 43520 u16 (16B aligned)
    u16*   W1f     = W0f + 43520;           // 65536 u16
    u16*   W4f     = W1f + 65536;           // 98304 u16
    float* out     = (float*)d_out;

    prep_kernel<<<(207360 + 255) / 256, 256, 0, stream>>>(Wb0, Wb1, Wff1, Wff2, Wta, Wtb, Wfc, W0f, W1f, W4f);
    sffA_kernel<<<BB * FF, 256, 0, stream>>>(x, c3, l3, c6, l6, c12, l12, c24, l24, meanbuf, x1);
    sffB_kernel<<<BB * 3, 256, 0, stream>>>(x1, c3, l3, c6, l6, c12, l12, c24, l24, x2, x3);
    scan_kernel<<<BB / 8, 512, 0, stream>>>(x1,
                                            (const uint4*)W0f, (const uint4*)W1f, (const uint4*)W4f,
                                            bb0, bb1, bff1, bff2, bta, btb, bfc, r1);
    fits_kernel<<<144, 256, 0, stream>>>(r1, x3, Wfits, x2, meanbuf, out);
}